// Round 1
// baseline (991.074 us; speedup 1.0000x reference)
//
#include <hip/hip_runtime.h>
#include <hip/hip_bf16.h>

// ---- problem constants ----
#define BL    2
#define LSEQ  1024
#define DMOD  1024
#define DIN   2048      // inner dim
#define NST   16        // d_state
#define DTRK  64        // dt rank
#define MR    (BL*LSEQ) // 2048 rows

typedef __bf16 bf16x8 __attribute__((ext_vector_type(8)));
typedef float  f32x4  __attribute__((ext_vector_type(4)));

#define LDT 40   // LDS row stride in bf16: 32 data + 8 pad (breaks bank aliasing, keeps 16B align)

__device__ __forceinline__ uint4 ldg16(const __hip_bfloat16* p, bool v) {
    if (v) return *(const uint4*)p;
    uint4 z; z.x = z.y = z.z = z.w = 0u; return z;
}

// C[M][N] = A[M][K] (bf16) * B[N][K]^T (bf16), fp32 accum, templated epilogue.
// MODE 0: e0=float* C
// MODE 1: e0=bf16* dtin(2048x64,+bias), e1=float* Bm(2048x16), e2=float* Cm(2048x16), bias=dtin_b
// MODE 2: e0=float* dt = softplus(acc + bias[n])
// MODE 3: e0=float* out = acc + res[m*N+n], e1=const float* res
template <int MODE>
__global__ __launch_bounds__(256, 2) void gemm_bt(
    const __hip_bfloat16* __restrict__ A, const __hip_bfloat16* __restrict__ Bw,
    int M, int N, int K,
    void* __restrict__ e0, void* __restrict__ e1, void* __restrict__ e2,
    const float* __restrict__ bias)
{
    __shared__ __hip_bfloat16 sA[128 * LDT];
    __shared__ __hip_bfloat16 sB[128 * LDT];

    const int m0 = blockIdx.y * 128;
    const int n0 = blockIdx.x * 128;
    const int tid = threadIdx.x;
    const int w = tid >> 6, lane = tid & 63;
    const int wm = (w >> 1) * 64, wn = (w & 1) * 64;
    const int lrow = lane & 15, lq = lane >> 4;

    // staging: 512 16B-chunks per tile; thread covers rows r0 and r0+64, quarter q0
    const int r0 = tid >> 2, q0 = tid & 3;

    f32x4 acc[4][4];
#pragma unroll
    for (int i = 0; i < 4; i++)
#pragma unroll
        for (int j = 0; j < 4; j++) { acc[i][j][0]=0.f; acc[i][j][1]=0.f; acc[i][j][2]=0.f; acc[i][j][3]=0.f; }

    const int nk = K >> 5;
    int c = q0 * 8;
    uint4 ra0 = ldg16(A  + (size_t)(m0 + r0)      * K + c, true);
    uint4 ra1 = ldg16(A  + (size_t)(m0 + r0 + 64) * K + c, true);
    uint4 rb0 = ldg16(Bw + (size_t)(n0 + r0)      * K + c, (n0 + r0)      < N);
    uint4 rb1 = ldg16(Bw + (size_t)(n0 + r0 + 64) * K + c, (n0 + r0 + 64) < N);

    for (int kb = 0; kb < nk; ++kb) {
        __syncthreads();
        *(uint4*)&sA[r0 * LDT + q0 * 8]        = ra0;
        *(uint4*)&sA[(r0 + 64) * LDT + q0 * 8] = ra1;
        *(uint4*)&sB[r0 * LDT + q0 * 8]        = rb0;
        *(uint4*)&sB[(r0 + 64) * LDT + q0 * 8] = rb1;
        if (kb + 1 < nk) {
            const int cc = (kb + 1) * 32 + q0 * 8;
            ra0 = ldg16(A  + (size_t)(m0 + r0)      * K + cc, true);
            ra1 = ldg16(A  + (size_t)(m0 + r0 + 64) * K + cc, true);
            rb0 = ldg16(Bw + (size_t)(n0 + r0)      * K + cc, (n0 + r0)      < N);
            rb1 = ldg16(Bw + (size_t)(n0 + r0 + 64) * K + cc, (n0 + r0 + 64) < N);
        }
        __syncthreads();

        bf16x8 af[4], bb[4];
#pragma unroll
        for (int mt = 0; mt < 4; mt++)
            af[mt] = *(const bf16x8*)&sA[(wm + mt * 16 + lrow) * LDT + lq * 8];
#pragma unroll
        for (int nt = 0; nt < 4; nt++)
            bb[nt] = *(const bf16x8*)&sB[(wn + nt * 16 + lrow) * LDT + lq * 8];
#pragma unroll
        for (int mt = 0; mt < 4; mt++)
#pragma unroll
            for (int nt = 0; nt < 4; nt++)
                acc[mt][nt] = __builtin_amdgcn_mfma_f32_16x16x32_bf16(af[mt], bb[nt], acc[mt][nt], 0, 0, 0);
    }

    // epilogue: C[row=(lane>>4)*4+r][col=lane&15]  (m89/m91-verified layout)
#pragma unroll
    for (int mt = 0; mt < 4; mt++) {
#pragma unroll
        for (int nt = 0; nt < 4; nt++) {
            const int gn = n0 + wn + nt * 16 + lrow;
            if (gn >= N) continue;
            const int gmb = m0 + wm + mt * 16 + lq * 4;
#pragma unroll
            for (int r = 0; r < 4; r++) {
                const int gm = gmb + r;
                const float v = acc[mt][nt][r];
                if (MODE == 0) {
                    ((float*)e0)[(size_t)gm * N + gn] = v;
                } else if (MODE == 1) {
                    if (gn < 64)       ((__hip_bfloat16*)e0)[(size_t)gm * 64 + gn] = __float2bfloat16(v + bias[gn]);
                    else if (gn < 80)  ((float*)e1)[(size_t)gm * 16 + (gn - 64)] = v;
                    else if (gn < 96)  ((float*)e2)[(size_t)gm * 16 + (gn - 80)] = v;
                } else if (MODE == 2) {
                    const float xx = v + bias[gn];
                    ((float*)e0)[(size_t)gm * N + gn] = (xx > 20.f) ? xx : log1pf(__expf(xx));
                } else { // MODE 3
                    ((float*)e0)[(size_t)gm * N + gn] = v + ((const float*)e1)[(size_t)gm * N + gn];
                }
            }
        }
    }
}

__global__ void f2b_kernel(const float* __restrict__ s, __hip_bfloat16* __restrict__ d, int n) {
    int i = blockIdx.x * blockDim.x + threadIdx.x;
    const int stride = gridDim.x * blockDim.x;
    for (; i < n; i += stride) d[i] = __float2bfloat16(s[i]);
}

__global__ void ln_kernel(const float* __restrict__ x, const float* __restrict__ g,
                          const float* __restrict__ b, __hip_bfloat16* __restrict__ xn) {
    const int row = blockIdx.x;          // 0..2047
    const int tid = threadIdx.x;         // 256
    const float4 v = ((const float4*)(x + (size_t)row * DMOD))[tid];
    float s  = v.x + v.y + v.z + v.w;
    float sq = v.x * v.x + v.y * v.y + v.z * v.z + v.w * v.w;
#pragma unroll
    for (int off = 32; off >= 1; off >>= 1) {
        s  += __shfl_down(s, off, 64);
        sq += __shfl_down(sq, off, 64);
    }
    __shared__ float red[8];
    const int w = tid >> 6, lane = tid & 63;
    if (lane == 0) { red[w] = s; red[4 + w] = sq; }
    __syncthreads();
    s  = red[0] + red[1] + red[2] + red[3];
    sq = red[4] + red[5] + red[6] + red[7];
    const float mean = s * (1.f / DMOD);
    float var = sq * (1.f / DMOD) - mean * mean;
    const float rstd = rsqrtf(var + 1e-5f);
    const int col = tid * 4;
    const float vv[4] = {v.x, v.y, v.z, v.w};
#pragma unroll
    for (int i = 0; i < 4; i++)
        xn[(size_t)row * DMOD + col + i] =
            __float2bfloat16((vv[i] - mean) * rstd * g[col + i] + b[col + i]);
}

// causal depthwise conv(4) + silu. xz holds [x_proj | z] (2048 x 4096).
__global__ void conv_silu_kernel(const float* __restrict__ xz, const float* __restrict__ cw,
                                 const float* __restrict__ cb, float* __restrict__ xcf,
                                 __hip_bfloat16* __restrict__ xcb) {
    const int m = blockIdx.y;                       // b*1024 + l
    const int d = blockIdx.x * 256 + threadIdx.x;   // 0..2047
    const int l = m & (LSEQ - 1);
    const int bb = m >> 10;
    float acc = cb[d];
#pragma unroll
    for (int k = 0; k < 4; k++) {
        const int ls = l - 3 + k;
        if (ls >= 0)
            acc += cw[d * 4 + k] * xz[((size_t)(bb << 10) + ls) * (2 * DIN) + d];
    }
    const float sv = acc / (1.f + __expf(-acc));
    xcf[(size_t)m * DIN + d] = sv;
    xcb[(size_t)m * DIN + d] = __float2bfloat16(sv);
}

// selective scan: thread = (b, d, n); 16 d-channels x 16 states per block.
__global__ __launch_bounds__(256) void scan_kernel(
    const float* __restrict__ dt, const float* __restrict__ u,
    const float* __restrict__ Bm, const float* __restrict__ Cm,
    const float* __restrict__ A_log, const float* __restrict__ Dp,
    const float* __restrict__ xz, __hip_bfloat16* __restrict__ y)
{
    const int blk = blockIdx.x;            // 0..255
    const int bb = blk >> 7;               // batch
    const int d0 = (blk & 127) * 16;
    const int tid = threadIdx.x;
    const int n = tid & 15, dl = tid >> 4;
    const int d = d0 + dl;
    const float a = -__expf(A_log[(size_t)d * NST + n]);
    const float Dd = Dp[d];
    const size_t base = (size_t)bb * LSEQ;
    float h = 0.f;
#pragma unroll 2
    for (int t = 0; t < LSEQ; t++) {
        const size_t row = base + t;
        const float dtv = dt[row * DIN + d];
        const float uv  = u[row * DIN + d];
        const float Bv  = Bm[row * NST + n];
        const float Cv  = Cm[row * NST + n];
        const float dA = __expf(dtv * a);
        h = h * dA + dtv * uv * Bv;
        float yp = h * Cv;
        yp += __shfl_xor(yp, 1, 16);
        yp += __shfl_xor(yp, 2, 16);
        yp += __shfl_xor(yp, 4, 16);
        yp += __shfl_xor(yp, 8, 16);
        if (n == 0) {
            const float zv = xz[row * (2 * DIN) + DIN + d];
            const float yv = (yp + uv * Dd) * (zv / (1.f + __expf(-zv)));
            y[row * DIN + d] = __float2bfloat16(yv);
        }
    }
}

extern "C" void kernel_launch(void* const* d_in, const int* in_sizes, int n_in,
                              void* d_out, int out_size, void* d_ws, size_t ws_size,
                              hipStream_t stream) {
    const float* x      = (const float*)d_in[0];
    const float* ln_g   = (const float*)d_in[1];
    const float* ln_b   = (const float*)d_in[2];
    const float* w_in   = (const float*)d_in[3];   // (4096,1024)
    const float* conv_w = (const float*)d_in[4];   // (2048,1,4)
    const float* conv_b = (const float*)d_in[5];
    const float* dtin_w = (const float*)d_in[6];   // (64,2048)
    const float* dtin_b = (const float*)d_in[7];
    const float* dt_w   = (const float*)d_in[8];   // (2048,64)
    const float* dt_b   = (const float*)d_in[9];
    const float* B_w    = (const float*)d_in[10];  // (16,2048)
    const float* C_w    = (const float*)d_in[11];
    const float* A_log  = (const float*)d_in[12];  // (2048,16)
    const float* Dp     = (const float*)d_in[13];
    const float* out_w  = (const float*)d_in[14];  // (1024,2048)
    float* out = (float*)d_out;

    char* ws = (char*)d_ws;
    auto alloc = [&](size_t bytes) { char* p = ws; ws += (bytes + 255) & ~255ull; return p; };
    __hip_bfloat16* w1b   = (__hip_bfloat16*)alloc((size_t)4096 * 1024 * 2);
    __hip_bfloat16* wpb   = (__hip_bfloat16*)alloc((size_t)96 * 2048 * 2);
    __hip_bfloat16* dtwb  = (__hip_bfloat16*)alloc((size_t)2048 * 64 * 2);
    __hip_bfloat16* owb   = (__hip_bfloat16*)alloc((size_t)1024 * 2048 * 2);
    __hip_bfloat16* xnb   = (__hip_bfloat16*)alloc((size_t)MR * DMOD * 2);
    float*          xz    = (float*)alloc((size_t)MR * 4096 * 4);
    float*          xcf   = (float*)alloc((size_t)MR * DIN * 4);
    __hip_bfloat16* xcb   = (__hip_bfloat16*)alloc((size_t)MR * DIN * 2);
    __hip_bfloat16* dtinb = (__hip_bfloat16*)alloc((size_t)MR * 64 * 2);
    float*          Bmf   = (float*)alloc((size_t)MR * NST * 4);
    float*          Cmf   = (float*)alloc((size_t)MR * NST * 4);
    float*          dtf   = (float*)alloc((size_t)MR * DIN * 4);
    __hip_bfloat16* yb    = (__hip_bfloat16*)alloc((size_t)MR * DIN * 2);

    // weight conversions (re-done every call; inputs restored by harness)
    f2b_kernel<<<1024, 256, 0, stream>>>(w_in, w1b, 4096 * 1024);
    f2b_kernel<<<256, 256, 0, stream>>>(dtin_w, wpb, 64 * 2048);
    f2b_kernel<<<128, 256, 0, stream>>>(B_w, wpb + 64 * 2048, 16 * 2048);
    f2b_kernel<<<128, 256, 0, stream>>>(C_w, wpb + 80 * 2048, 16 * 2048);
    f2b_kernel<<<256, 256, 0, stream>>>(dt_w, dtwb, 2048 * 64);
    f2b_kernel<<<1024, 256, 0, stream>>>(out_w, owb, 1024 * 2048);

    ln_kernel<<<MR, 256, 0, stream>>>(x, ln_g, ln_b, xnb);

    // xz = xn @ in_proj_w^T : (2048 x 4096), K=1024
    gemm_bt<0><<<dim3(32, 16), 256, 0, stream>>>(xnb, w1b, MR, 4096, 1024, xz, nullptr, nullptr, nullptr);

    conv_silu_kernel<<<dim3(8, MR), 256, 0, stream>>>(xz, conv_w, conv_b, xcf, xcb);

    // [dtin | Bm | Cm] = x_conv @ [dtin_w;B_w;C_w]^T : (2048 x 96), K=2048
    gemm_bt<1><<<dim3(1, 16), 256, 0, stream>>>(xcb, wpb, MR, 96, 2048, dtinb, Bmf, Cmf, dtin_b);

    // dt = softplus(dtin @ dt_w^T + dt_b) : (2048 x 2048), K=64
    gemm_bt<2><<<dim3(16, 16), 256, 0, stream>>>(dtinb, dtwb, MR, DIN, 64, dtf, nullptr, nullptr, dt_b);

    scan_kernel<<<256, 256, 0, stream>>>(dtf, xcf, Bmf, Cmf, A_log, Dp, xz, yb);

    // out = y @ out_w^T + residual : (2048 x 1024), K=2048
    gemm_bt<3><<<dim3(8, 16), 256, 0, stream>>>(yb, owb, MR, DMOD, 2048, out, (void*)x, nullptr, nullptr);
}

// Round 2
// 371.447 us; speedup vs baseline: 2.6681x; 2.6681x over previous
//
#include <hip/hip_runtime.h>
#include <hip/hip_bf16.h>

// ---- problem constants ----
#define BL    2
#define LSEQ  1024
#define DMOD  1024
#define DIN   2048      // inner dim
#define NST   16        // d_state
#define DTRK  64        // dt rank
#define MR    (BL*LSEQ) // 2048 rows

// chunked scan: C chunks of T timesteps
#define CCH 32
#define TCH 32          // LSEQ / CCH

typedef __bf16 bf16x8 __attribute__((ext_vector_type(8)));
typedef float  f32x4  __attribute__((ext_vector_type(4)));

#define LDT 40   // LDS row stride in bf16: 32 data + 8 pad (breaks bank aliasing, keeps 16B align)

__device__ __forceinline__ uint4 ldg16(const __hip_bfloat16* p, bool v) {
    if (v) return *(const uint4*)p;
    uint4 z; z.x = z.y = z.z = z.w = 0u; return z;
}

// C[M][N] = A[M][K] (bf16) * B[N][K]^T (bf16), fp32 accum, templated epilogue.
// MODE 0: e0=float* C
// MODE 1: e0=bf16* dtin(2048x64,+bias), e1=float* Bm(2048x16), e2=float* Cm(2048x16), bias=dtin_b
// MODE 2: e0=float* dt = softplus(acc + bias[n])
// MODE 3: e0=float* out = acc + res[m*N+n], e1=const float* res
template <int MODE>
__global__ __launch_bounds__(256, 2) void gemm_bt(
    const __hip_bfloat16* __restrict__ A, const __hip_bfloat16* __restrict__ Bw,
    int M, int N, int K,
    void* __restrict__ e0, void* __restrict__ e1, void* __restrict__ e2,
    const float* __restrict__ bias)
{
    __shared__ __hip_bfloat16 sA[128 * LDT];
    __shared__ __hip_bfloat16 sB[128 * LDT];

    const int m0 = blockIdx.y * 128;
    const int n0 = blockIdx.x * 128;
    const int tid = threadIdx.x;
    const int w = tid >> 6, lane = tid & 63;
    const int wm = (w >> 1) * 64, wn = (w & 1) * 64;
    const int lrow = lane & 15, lq = lane >> 4;

    // staging: 512 16B-chunks per tile; thread covers rows r0 and r0+64, quarter q0
    const int r0 = tid >> 2, q0 = tid & 3;

    f32x4 acc[4][4];
#pragma unroll
    for (int i = 0; i < 4; i++)
#pragma unroll
        for (int j = 0; j < 4; j++) { acc[i][j][0]=0.f; acc[i][j][1]=0.f; acc[i][j][2]=0.f; acc[i][j][3]=0.f; }

    const int nk = K >> 5;
    int c = q0 * 8;
    uint4 ra0 = ldg16(A  + (size_t)(m0 + r0)      * K + c, true);
    uint4 ra1 = ldg16(A  + (size_t)(m0 + r0 + 64) * K + c, true);
    uint4 rb0 = ldg16(Bw + (size_t)(n0 + r0)      * K + c, (n0 + r0)      < N);
    uint4 rb1 = ldg16(Bw + (size_t)(n0 + r0 + 64) * K + c, (n0 + r0 + 64) < N);

    for (int kb = 0; kb < nk; ++kb) {
        __syncthreads();
        *(uint4*)&sA[r0 * LDT + q0 * 8]        = ra0;
        *(uint4*)&sA[(r0 + 64) * LDT + q0 * 8] = ra1;
        *(uint4*)&sB[r0 * LDT + q0 * 8]        = rb0;
        *(uint4*)&sB[(r0 + 64) * LDT + q0 * 8] = rb1;
        if (kb + 1 < nk) {
            const int cc = (kb + 1) * 32 + q0 * 8;
            ra0 = ldg16(A  + (size_t)(m0 + r0)      * K + cc, true);
            ra1 = ldg16(A  + (size_t)(m0 + r0 + 64) * K + cc, true);
            rb0 = ldg16(Bw + (size_t)(n0 + r0)      * K + cc, (n0 + r0)      < N);
            rb1 = ldg16(Bw + (size_t)(n0 + r0 + 64) * K + cc, (n0 + r0 + 64) < N);
        }
        __syncthreads();

        bf16x8 af[4], bb[4];
#pragma unroll
        for (int mt = 0; mt < 4; mt++)
            af[mt] = *(const bf16x8*)&sA[(wm + mt * 16 + lrow) * LDT + lq * 8];
#pragma unroll
        for (int nt = 0; nt < 4; nt++)
            bb[nt] = *(const bf16x8*)&sB[(wn + nt * 16 + lrow) * LDT + lq * 8];
#pragma unroll
        for (int mt = 0; mt < 4; mt++)
#pragma unroll
            for (int nt = 0; nt < 4; nt++)
                acc[mt][nt] = __builtin_amdgcn_mfma_f32_16x16x32_bf16(af[mt], bb[nt], acc[mt][nt], 0, 0, 0);
    }

    // epilogue: C[row=(lane>>4)*4+r][col=lane&15]  (m89/m91-verified layout)
#pragma unroll
    for (int mt = 0; mt < 4; mt++) {
#pragma unroll
        for (int nt = 0; nt < 4; nt++) {
            const int gn = n0 + wn + nt * 16 + lrow;
            if (gn >= N) continue;
            const int gmb = m0 + wm + mt * 16 + lq * 4;
#pragma unroll
            for (int r = 0; r < 4; r++) {
                const int gm = gmb + r;
                const float v = acc[mt][nt][r];
                if (MODE == 0) {
                    ((float*)e0)[(size_t)gm * N + gn] = v;
                } else if (MODE == 1) {
                    if (gn < 64)       ((__hip_bfloat16*)e0)[(size_t)gm * 64 + gn] = __float2bfloat16(v + bias[gn]);
                    else if (gn < 80)  ((float*)e1)[(size_t)gm * 16 + (gn - 64)] = v;
                    else if (gn < 96)  ((float*)e2)[(size_t)gm * 16 + (gn - 80)] = v;
                } else if (MODE == 2) {
                    const float xx = v + bias[gn];
                    ((float*)e0)[(size_t)gm * N + gn] = (xx > 20.f) ? xx : log1pf(__expf(xx));
                } else { // MODE 3
                    ((float*)e0)[(size_t)gm * N + gn] = v + ((const float*)e1)[(size_t)gm * N + gn];
                }
            }
        }
    }
}

__global__ void f2b_kernel(const float* __restrict__ s, __hip_bfloat16* __restrict__ d, int n) {
    int i = blockIdx.x * blockDim.x + threadIdx.x;
    const int stride = gridDim.x * blockDim.x;
    for (; i < n; i += stride) d[i] = __float2bfloat16(s[i]);
}

__global__ void ln_kernel(const float* __restrict__ x, const float* __restrict__ g,
                          const float* __restrict__ b, __hip_bfloat16* __restrict__ xn) {
    const int row = blockIdx.x;          // 0..2047
    const int tid = threadIdx.x;         // 256
    const float4 v = ((const float4*)(x + (size_t)row * DMOD))[tid];
    float s  = v.x + v.y + v.z + v.w;
    float sq = v.x * v.x + v.y * v.y + v.z * v.z + v.w * v.w;
#pragma unroll
    for (int off = 32; off >= 1; off >>= 1) {
        s  += __shfl_down(s, off, 64);
        sq += __shfl_down(sq, off, 64);
    }
    __shared__ float red[8];
    const int w = tid >> 6, lane = tid & 63;
    if (lane == 0) { red[w] = s; red[4 + w] = sq; }
    __syncthreads();
    s  = red[0] + red[1] + red[2] + red[3];
    sq = red[4] + red[5] + red[6] + red[7];
    const float mean = s * (1.f / DMOD);
    float var = sq * (1.f / DMOD) - mean * mean;
    const float rstd = rsqrtf(var + 1e-5f);
    const int col = tid * 4;
    const float vv[4] = {v.x, v.y, v.z, v.w};
#pragma unroll
    for (int i = 0; i < 4; i++)
        xn[(size_t)row * DMOD + col + i] =
            __float2bfloat16((vv[i] - mean) * rstd * g[col + i] + b[col + i]);
}

// causal depthwise conv(4) + silu. xz holds [x_proj | z] (2048 x 4096).
__global__ void conv_silu_kernel(const float* __restrict__ xz, const float* __restrict__ cw,
                                 const float* __restrict__ cb, float* __restrict__ xcf,
                                 __hip_bfloat16* __restrict__ xcb) {
    const int m = blockIdx.y;                       // b*1024 + l
    const int d = blockIdx.x * 256 + threadIdx.x;   // 0..2047
    const int l = m & (LSEQ - 1);
    const int bb = m >> 10;
    float acc = cb[d];
#pragma unroll
    for (int k = 0; k < 4; k++) {
        const int ls = l - 3 + k;
        if (ls >= 0)
            acc += cw[d * 4 + k] * xz[((size_t)(bb << 10) + ls) * (2 * DIN) + d];
    }
    const float sv = acc / (1.f + __expf(-acc));
    xcf[(size_t)m * DIN + d] = sv;
    xcb[(size_t)m * DIN + d] = __float2bfloat16(sv);
}

// ===================== chunked selective scan =====================
// h_t = dA_t * h_{t-1} + dt_t*u_t*B_t  is linear in h -> associative.
// p1: per-chunk (A_prod, B_acc) with h_start=0.  grid: (b, d-tile, chunk)
// p2: serial prefix over the 32 chunks per (b,d,n) -> h_start per chunk
// p3: re-run chunk scans seeded with h_start, emit y.

// block = 256 threads = 16 d-channels x 16 states; blockIdx decodes (b, dtile, chunk)
__global__ __launch_bounds__(256) void scan_p1(
    const float* __restrict__ dt, const float* __restrict__ u,
    const float* __restrict__ Bm, const float* __restrict__ A_log,
    float* __restrict__ Aprod, float* __restrict__ Bacc)
{
    __shared__ float sdt[TCH * 16], su[TCH * 16], sB[TCH * 16];
    const int blk = blockIdx.x;
    const int bb = blk / (128 * CCH);
    const int rem = blk % (128 * CCH);
    const int dtile = rem / CCH, c = rem % CCH;
    const int d0 = dtile * 16;
    const int tid = threadIdx.x;
    const int row0 = bb * LSEQ + c * TCH;

#pragma unroll
    for (int j = 0; j < (TCH * 16) / 256; j++) {
        const int flat = tid + j * 256;
        const int t = flat >> 4, dd = flat & 15;
        sdt[flat] = dt[(size_t)(row0 + t) * DIN + d0 + dd];
        su[flat]  = u [(size_t)(row0 + t) * DIN + d0 + dd];
        sB[flat]  = Bm[(size_t)row0 * NST + flat];        // contiguous chunk
    }
    __syncthreads();

    const int n = tid & 15, dl = tid >> 4;
    const int d = d0 + dl;
    const float a = -__expf(A_log[(size_t)d * NST + n]);
    float h = 0.f, Ap = 1.f;
#pragma unroll 4
    for (int t = 0; t < TCH; t++) {
        const float dtv = sdt[t * 16 + dl];
        const float uv  = su [t * 16 + dl];
        const float Bv  = sB [t * 16 + n];
        const float dA = __expf(dtv * a);
        Ap *= dA;
        h = h * dA + dtv * uv * Bv;
    }
    const size_t idx = (((size_t)bb * CCH + c) * DIN + d) * NST + n;
    Aprod[idx] = Ap;
    Bacc[idx]  = h;
}

// 65536 threads; thread = (b, d, n); serial over 32 chunks (coalesced: consecutive
// threads -> consecutive (d,n) -> contiguous addresses within a chunk slab)
__global__ __launch_bounds__(256) void scan_p2(
    const float* __restrict__ Aprod, const float* __restrict__ Bacc,
    float* __restrict__ hstart)
{
    const int i = blockIdx.x * 256 + threadIdx.x;
    const int bb = i >> 15;          // DIN*NST = 32768 per batch
    const int dn = i & 32767;
    float hs = 0.f;
#pragma unroll
    for (int c = 0; c < CCH; c++) {
        const size_t idx = (((size_t)bb * CCH + c) << 15) + dn;
        hstart[idx] = hs;
        hs = Aprod[idx] * hs + Bacc[idx];
    }
}

__global__ __launch_bounds__(256) void scan_p3(
    const float* __restrict__ dt, const float* __restrict__ u,
    const float* __restrict__ Bm, const float* __restrict__ Cm,
    const float* __restrict__ A_log, const float* __restrict__ Dp,
    const float* __restrict__ xz, const float* __restrict__ hstart,
    __hip_bfloat16* __restrict__ y)
{
    __shared__ float sdt[TCH * 16], su[TCH * 16], sB[TCH * 16], sC[TCH * 16];
    const int blk = blockIdx.x;
    const int bb = blk / (128 * CCH);
    const int rem = blk % (128 * CCH);
    const int dtile = rem / CCH, c = rem % CCH;
    const int d0 = dtile * 16;
    const int tid = threadIdx.x;
    const int row0 = bb * LSEQ + c * TCH;

#pragma unroll
    for (int j = 0; j < (TCH * 16) / 256; j++) {
        const int flat = tid + j * 256;
        const int t = flat >> 4, dd = flat & 15;
        sdt[flat] = dt[(size_t)(row0 + t) * DIN + d0 + dd];
        su[flat]  = u [(size_t)(row0 + t) * DIN + d0 + dd];
        sB[flat]  = Bm[(size_t)row0 * NST + flat];
        sC[flat]  = Cm[(size_t)row0 * NST + flat];
    }
    __syncthreads();

    const int n = tid & 15, dl = tid >> 4;
    const int d = d0 + dl;
    const float a = -__expf(A_log[(size_t)d * NST + n]);
    const float Dd = Dp[d];
    const size_t idx = (((size_t)bb * CCH + c) * DIN + d) * NST + n;
    float h = hstart[idx];
#pragma unroll 2
    for (int t = 0; t < TCH; t++) {
        const float dtv = sdt[t * 16 + dl];
        const float uv  = su [t * 16 + dl];
        const float Bv  = sB [t * 16 + n];
        const float dA = __expf(dtv * a);
        h = h * dA + dtv * uv * Bv;
        float yp = h * sC[t * 16 + n];
        yp += __shfl_xor(yp, 1, 16);
        yp += __shfl_xor(yp, 2, 16);
        yp += __shfl_xor(yp, 4, 16);
        yp += __shfl_xor(yp, 8, 16);
        if (n == 0) {
            const size_t row = (size_t)row0 + t;
            const float zv = xz[row * (2 * DIN) + DIN + d];
            const float yv = (yp + uv * Dd) * (zv / (1.f + __expf(-zv)));
            y[row * DIN + d] = __float2bfloat16(yv);
        }
    }
}

extern "C" void kernel_launch(void* const* d_in, const int* in_sizes, int n_in,
                              void* d_out, int out_size, void* d_ws, size_t ws_size,
                              hipStream_t stream) {
    const float* x      = (const float*)d_in[0];
    const float* ln_g   = (const float*)d_in[1];
    const float* ln_b   = (const float*)d_in[2];
    const float* w_in   = (const float*)d_in[3];   // (4096,1024)
    const float* conv_w = (const float*)d_in[4];   // (2048,1,4)
    const float* conv_b = (const float*)d_in[5];
    const float* dtin_w = (const float*)d_in[6];   // (64,2048)
    const float* dtin_b = (const float*)d_in[7];
    const float* dt_w   = (const float*)d_in[8];   // (2048,64)
    const float* dt_b   = (const float*)d_in[9];
    const float* B_w    = (const float*)d_in[10];  // (16,2048)
    const float* C_w    = (const float*)d_in[11];
    const float* A_log  = (const float*)d_in[12];  // (2048,16)
    const float* Dp     = (const float*)d_in[13];
    const float* out_w  = (const float*)d_in[14];  // (1024,2048)
    float* out = (float*)d_out;

    char* ws = (char*)d_ws;
    auto alloc = [&](size_t bytes) { char* p = ws; ws += (bytes + 255) & ~255ull; return p; };
    __hip_bfloat16* w1b   = (__hip_bfloat16*)alloc((size_t)4096 * 1024 * 2);
    __hip_bfloat16* wpb   = (__hip_bfloat16*)alloc((size_t)96 * 2048 * 2);
    __hip_bfloat16* dtwb  = (__hip_bfloat16*)alloc((size_t)2048 * 64 * 2);
    __hip_bfloat16* owb   = (__hip_bfloat16*)alloc((size_t)1024 * 2048 * 2);
    __hip_bfloat16* xnb   = (__hip_bfloat16*)alloc((size_t)MR * DMOD * 2);
    float*          xz    = (float*)alloc((size_t)MR * 4096 * 4);
    float*          xcf   = (float*)alloc((size_t)MR * DIN * 4);
    __hip_bfloat16* xcb   = (__hip_bfloat16*)alloc((size_t)MR * DIN * 2);
    __hip_bfloat16* dtinb = (__hip_bfloat16*)alloc((size_t)MR * 64 * 2);
    float*          Bmf   = (float*)alloc((size_t)MR * NST * 4);
    float*          Cmf   = (float*)alloc((size_t)MR * NST * 4);
    float*          dtf   = (float*)alloc((size_t)MR * DIN * 4);
    __hip_bfloat16* yb    = (__hip_bfloat16*)alloc((size_t)MR * DIN * 2);
    float*          Aprod = (float*)alloc((size_t)BL * CCH * DIN * NST * 4);
    float*          Bacc  = (float*)alloc((size_t)BL * CCH * DIN * NST * 4);
    float*          hstart= (float*)alloc((size_t)BL * CCH * DIN * NST * 4);

    // weight conversions (re-done every call; inputs restored by harness)
    f2b_kernel<<<1024, 256, 0, stream>>>(w_in, w1b, 4096 * 1024);
    f2b_kernel<<<256, 256, 0, stream>>>(dtin_w, wpb, 64 * 2048);
    f2b_kernel<<<128, 256, 0, stream>>>(B_w, wpb + 64 * 2048, 16 * 2048);
    f2b_kernel<<<128, 256, 0, stream>>>(C_w, wpb + 80 * 2048, 16 * 2048);
    f2b_kernel<<<256, 256, 0, stream>>>(dt_w, dtwb, 2048 * 64);
    f2b_kernel<<<1024, 256, 0, stream>>>(out_w, owb, 1024 * 2048);

    ln_kernel<<<MR, 256, 0, stream>>>(x, ln_g, ln_b, xnb);

    // xz = xn @ in_proj_w^T : (2048 x 4096), K=1024
    gemm_bt<0><<<dim3(32, 16), 256, 0, stream>>>(xnb, w1b, MR, 4096, 1024, xz, nullptr, nullptr, nullptr);

    conv_silu_kernel<<<dim3(8, MR), 256, 0, stream>>>(xz, conv_w, conv_b, xcf, xcb);

    // [dtin | Bm | Cm] = x_conv @ [dtin_w;B_w;C_w]^T : (2048 x 96), K=2048
    gemm_bt<1><<<dim3(1, 16), 256, 0, stream>>>(xcb, wpb, MR, 96, 2048, dtinb, Bmf, Cmf, dtin_b);

    // dt = softplus(dtin @ dt_w^T + dt_b) : (2048 x 2048), K=64
    gemm_bt<2><<<dim3(16, 16), 256, 0, stream>>>(dtinb, dtwb, MR, DIN, 64, dtf, nullptr, nullptr, dt_b);

    // chunked selective scan
    scan_p1<<<BL * 128 * CCH, 256, 0, stream>>>(dtf, xcf, Bmf, A_log, Aprod, Bacc);
    scan_p2<<<BL * DIN * NST / 256, 256, 0, stream>>>(Aprod, Bacc, hstart);
    scan_p3<<<BL * 128 * CCH, 256, 0, stream>>>(dtf, xcf, Bmf, Cmf, A_log, Dp, xz, hstart, yb);

    // out = y @ out_w^T + residual : (2048 x 1024), K=2048
    gemm_bt<3><<<dim3(8, 16), 256, 0, stream>>>(yb, owb, MR, DMOD, 2048, out, (void*)x, nullptr, nullptr);
}

// Round 3
// 288.817 us; speedup vs baseline: 3.4315x; 1.2861x over previous
//
#include <hip/hip_runtime.h>
#include <hip/hip_bf16.h>
#include <cstdint>

// ---- problem constants ----
#define BL    2
#define LSEQ  1024
#define DMOD  1024
#define DIN   2048      // inner dim
#define NST   16        // d_state
#define DTRK  64        // dt rank
#define MR    (BL*LSEQ) // 2048 rows

// chunked scan: C chunks of T timesteps
#define CCH 32
#define TCH 32          // LSEQ / CCH
#define KSPLIT 8        // split-K for the thin (N=96) GEMM

typedef __bf16 bf16x8 __attribute__((ext_vector_type(8)));
typedef float  f32x4  __attribute__((ext_vector_type(4)));

#if __has_builtin(__builtin_amdgcn_exp2f)
#define EXP2F(x) __builtin_amdgcn_exp2f(x)
#else
#define EXP2F(x) exp2f(x)
#endif
#define LOG2E 1.4426950408889634f

// async global->LDS, 16B per lane. LDS dest = wave-uniform base + lane*16 (m104).
__device__ __forceinline__ void glds16(const void* g, const void* l) {
    __builtin_amdgcn_global_load_lds(
        (__attribute__((address_space(1))) void*)(uintptr_t)(g),
        (__attribute__((address_space(3))) void*)(uint32_t)(uintptr_t)(l),
        16, 0, 0);
}

// C[M][N] = A[M][K] (bf16,lda) * B[N][K]^T (bf16,ldb), fp32 accum.
// K-offset = blockIdx.z * Ksl (split-K). Ksl must be multiple of 32.
// MODE 0: e0=float* xproj (gn<2048), e1=bf16* zs = silu(acc) (gn>=2048)   [in_proj]
// MODE 1: e0=float* partial[(z*M+gm)*96+gn]                               [dtin/B/C, split-K]
// MODE 2: e0=float* dt = softplus(acc + bias[gn])                         [dt proj]
// MODE 3: e0=float* out = acc + res[gm*N+gn], e1=const float* res         [out proj]
template <int MODE>
__global__ __launch_bounds__(256, 2) void gemm_bt(
    const __hip_bfloat16* __restrict__ A, int lda,
    const __hip_bfloat16* __restrict__ Bw, int ldb,
    int M, int N, int Ksl,
    void* __restrict__ e0, void* __restrict__ e1,
    const float* __restrict__ bias)
{
    __shared__ __align__(16) __hip_bfloat16 sA[128 * 32];
    __shared__ __align__(16) __hip_bfloat16 sB[128 * 32];

    const int m0 = blockIdx.y * 128;
    const int n0 = blockIdx.x * 128;
    const int k0 = blockIdx.z * Ksl;
    const int tid = threadIdx.x;
    const int w = tid >> 6, lane = tid & 63;
    const int wm = (w >> 1) * 64, wn = (w & 1) * 64;
    const int lrow = lane & 15, lq = lane >> 4;

    // staging map: thread tid -> sA byte offset tid*16 (row=tid>>2, 16B-quarter=tid&3)
    const int r0 = tid >> 2, q0 = tid & 3;
    const __hip_bfloat16* pa0 = A  + (size_t)(m0 + r0)      * lda + k0 + q0 * 8;
    const __hip_bfloat16* pa1 = A  + (size_t)(m0 + r0 + 64) * lda + k0 + q0 * 8;
    const __hip_bfloat16* pb0 = Bw + (size_t)(n0 + r0)      * ldb + k0 + q0 * 8;
    const __hip_bfloat16* pb1 = Bw + (size_t)(n0 + r0 + 64) * ldb + k0 + q0 * 8;
    // NOTE (MODE 1): rows n>=96 of Bw read past the 96-row weight slab into adjacent
    // workspace — finite garbage, columns discarded in epilogue (gn>=N guard).

    f32x4 acc[4][4];
#pragma unroll
    for (int i = 0; i < 4; i++)
#pragma unroll
        for (int j = 0; j < 4; j++) { acc[i][j][0]=0.f; acc[i][j][1]=0.f; acc[i][j][2]=0.f; acc[i][j][3]=0.f; }

    const int nk = Ksl >> 5;
    for (int kb = 0; kb < nk; ++kb) {
        __syncthreads();                    // prev iter's ds_reads done before DMA overwrite
        glds16(pa0, &sA[tid * 8]);
        glds16(pa1, &sA[2048 + tid * 8]);
        glds16(pb0, &sB[tid * 8]);
        glds16(pb1, &sB[2048 + tid * 8]);
        pa0 += 32; pa1 += 32; pb0 += 32; pb1 += 32;
        __syncthreads();                    // compiler emits vmcnt(0) drain here (m97 structure)

        bf16x8 af[4], bb[4];
#pragma unroll
        for (int mt = 0; mt < 4; mt++)
            af[mt] = *(const bf16x8*)&sA[(wm + mt * 16 + lrow) * 32 + lq * 8];
#pragma unroll
        for (int nt = 0; nt < 4; nt++)
            bb[nt] = *(const bf16x8*)&sB[(wn + nt * 16 + lrow) * 32 + lq * 8];
#pragma unroll
        for (int mt = 0; mt < 4; mt++)
#pragma unroll
            for (int nt = 0; nt < 4; nt++)
                acc[mt][nt] = __builtin_amdgcn_mfma_f32_16x16x32_bf16(af[mt], bb[nt], acc[mt][nt], 0, 0, 0);
    }

    // epilogue: C[row=(lane>>4)*4+r][col=lane&15]  (m89/m91-verified layout)
#pragma unroll
    for (int mt = 0; mt < 4; mt++) {
#pragma unroll
        for (int nt = 0; nt < 4; nt++) {
            const int gn = n0 + wn + nt * 16 + lrow;
            if (gn >= N) continue;
            const int gmb = m0 + wm + mt * 16 + lq * 4;
#pragma unroll
            for (int r = 0; r < 4; r++) {
                const int gm = gmb + r;
                const float v = acc[mt][nt][r];
                if (MODE == 0) {
                    if (gn < DIN) ((float*)e0)[(size_t)gm * DIN + gn] = v;
                    else {
                        const float s = v / (1.f + __expf(-v));
                        ((__hip_bfloat16*)e1)[(size_t)gm * DIN + (gn - DIN)] = __float2bfloat16(s);
                    }
                } else if (MODE == 1) {
                    ((float*)e0)[((size_t)blockIdx.z * M + gm) * 96 + gn] = v;
                } else if (MODE == 2) {
                    const float xx = v + bias[gn];
                    ((float*)e0)[(size_t)gm * N + gn] = (xx > 20.f) ? xx : log1pf(__expf(xx));
                } else { // MODE 3
                    ((float*)e0)[(size_t)gm * N + gn] = v + ((const float*)e1)[(size_t)gm * N + gn];
                }
            }
        }
    }
}

// reduce split-K partials; emit dtin (bf16, +bias), Bm, Cm (float)
__global__ void ep1_kernel(const float* __restrict__ part, const float* __restrict__ dtin_b,
                           __hip_bfloat16* __restrict__ dtinb, float* __restrict__ Bmf,
                           float* __restrict__ Cmf) {
    const int i = blockIdx.x * 256 + threadIdx.x;
    if (i >= MR * 96) return;
    const int m = i / 96, n = i - m * 96;
    float s = 0.f;
#pragma unroll
    for (int z = 0; z < KSPLIT; z++) s += part[((size_t)z * MR + m) * 96 + n];
    if (n < 64)      dtinb[(size_t)m * 64 + n] = __float2bfloat16(s + dtin_b[n]);
    else if (n < 80) Bmf[(size_t)m * NST + (n - 64)] = s;
    else             Cmf[(size_t)m * NST + (n - 80)] = s;
}

// all weight f32->bf16 conversions in one launch (vec4)
__global__ void cvt_all(const float* __restrict__ w_in, const float* __restrict__ dtin_w,
                        const float* __restrict__ B_w, const float* __restrict__ C_w,
                        const float* __restrict__ dt_w, const float* __restrict__ out_w,
                        __hip_bfloat16* __restrict__ w1b, __hip_bfloat16* __restrict__ wpb,
                        __hip_bfloat16* __restrict__ dtwb, __hip_bfloat16* __restrict__ owb) {
    const int NV = (4194304 + 131072 + 32768 + 32768 + 131072 + 2097152) / 4;
    for (int v = blockIdx.x * 256 + threadIdx.x; v < NV; v += gridDim.x * 256) {
        const int i = v * 4;
        const float* s; __hip_bfloat16* dk;
        if      (i < 4194304) { s = w_in   + i;             dk = w1b  + i; }
        else if (i < 4325376) { s = dtin_w + (i - 4194304); dk = wpb  + (i - 4194304); }
        else if (i < 4358144) { s = B_w    + (i - 4325376); dk = wpb  + 131072 + (i - 4325376); }
        else if (i < 4390912) { s = C_w    + (i - 4358144); dk = wpb  + 163840 + (i - 4358144); }
        else if (i < 4521984) { s = dt_w   + (i - 4390912); dk = dtwb + (i - 4390912); }
        else                  { s = out_w  + (i - 4521984); dk = owb  + (i - 4521984); }
        const float4 f = *(const float4*)s;
        __hip_bfloat16 t0 = __float2bfloat16(f.x), t1 = __float2bfloat16(f.y);
        __hip_bfloat16 t2 = __float2bfloat16(f.z), t3 = __float2bfloat16(f.w);
        ushort4 o;
        o.x = *(unsigned short*)&t0; o.y = *(unsigned short*)&t1;
        o.z = *(unsigned short*)&t2; o.w = *(unsigned short*)&t3;
        *(ushort4*)dk = o;
    }
}

__global__ void ln_kernel(const float* __restrict__ x, const float* __restrict__ g,
                          const float* __restrict__ b, __hip_bfloat16* __restrict__ xn) {
    const int row = blockIdx.x;
    const int tid = threadIdx.x;
    const float4 v = ((const float4*)(x + (size_t)row * DMOD))[tid];
    float s  = v.x + v.y + v.z + v.w;
    float sq = v.x * v.x + v.y * v.y + v.z * v.z + v.w * v.w;
#pragma unroll
    for (int off = 32; off >= 1; off >>= 1) {
        s  += __shfl_down(s, off, 64);
        sq += __shfl_down(sq, off, 64);
    }
    __shared__ float red[8];
    const int w = tid >> 6, lane = tid & 63;
    if (lane == 0) { red[w] = s; red[4 + w] = sq; }
    __syncthreads();
    s  = red[0] + red[1] + red[2] + red[3];
    sq = red[4] + red[5] + red[6] + red[7];
    const float mean = s * (1.f / DMOD);
    const float rstd = rsqrtf(sq * (1.f / DMOD) - mean * mean + 1e-5f);
    const int col = tid * 4;
    const float vv[4] = {v.x, v.y, v.z, v.w};
#pragma unroll
    for (int i = 0; i < 4; i++)
        xn[(size_t)row * DMOD + col + i] =
            __float2bfloat16((vv[i] - mean) * rstd * g[col + i] + b[col + i]);
}

// causal depthwise conv(4) + silu over x_proj (2048 x 2048 float), rolling registers.
// grid: (8 d-tiles of 256, 32 m-ranges of 64). 64|1024 so ranges never straddle batches.
__global__ void conv_silu_kernel(const float* __restrict__ xp, const float* __restrict__ cw,
                                 const float* __restrict__ cb, float* __restrict__ xcf,
                                 __hip_bfloat16* __restrict__ xcb) {
    const int d = blockIdx.x * 256 + threadIdx.x;
    const int m0 = blockIdx.y * 64;
    const int l0 = m0 & (LSEQ - 1);
    const float w0 = cw[d * 4], w1 = cw[d * 4 + 1], w2 = cw[d * 4 + 2], w3 = cw[d * 4 + 3];
    const float cbd = cb[d];
    float x0 = 0.f, x1 = 0.f, x2 = 0.f;
    if (l0 != 0) {
        x0 = xp[(size_t)(m0 - 3) * DIN + d];
        x1 = xp[(size_t)(m0 - 2) * DIN + d];
        x2 = xp[(size_t)(m0 - 1) * DIN + d];
    }
#pragma unroll 4
    for (int i = 0; i < 64; i++) {
        const float x3 = xp[(size_t)(m0 + i) * DIN + d];
        const float a = cbd + w0 * x0 + w1 * x1 + w2 * x2 + w3 * x3;
        const float sv = a / (1.f + __expf(-a));
        xcf[(size_t)(m0 + i) * DIN + d] = sv;
        xcb[(size_t)(m0 + i) * DIN + d] = __float2bfloat16(sv);
        x0 = x1; x1 = x2; x2 = x3;
    }
}

// ===================== chunked selective scan =====================
// thread = (b, d, n-half, chunk): 8 h-states in registers, no shuffle tree.
// block: 256 thr = 128 d x 2 nh, one chunk. grid decode: blk = ((bb*32+c)*16+dtile)

__global__ __launch_bounds__(256) void scan_p1(
    const float* __restrict__ dt, const float* __restrict__ u,
    const float* __restrict__ Bm, const float* __restrict__ A_log,
    float* __restrict__ Aprod, float* __restrict__ Bacc)
{
    __shared__ float sB[TCH * NST];
    const int blk = blockIdx.x;
    const int bb = blk >> 9, c = (blk >> 4) & 31, dtile = blk & 15;
    const int tid = threadIdx.x;
    const int nh = tid & 1, dl = tid >> 1;
    const int d = dtile * 128 + dl;
    const int row0 = bb * LSEQ + c * TCH;

    sB[tid]       = Bm[(size_t)row0 * NST + tid];
    sB[tid + 256] = Bm[(size_t)row0 * NST + tid + 256];
    __syncthreads();

    float a2[8];
    {
        const float4 al0 = *(const float4*)&A_log[(size_t)d * NST + nh * 8];
        const float4 al1 = *(const float4*)&A_log[(size_t)d * NST + nh * 8 + 4];
        a2[0] = -__expf(al0.x) * LOG2E; a2[1] = -__expf(al0.y) * LOG2E;
        a2[2] = -__expf(al0.z) * LOG2E; a2[3] = -__expf(al0.w) * LOG2E;
        a2[4] = -__expf(al1.x) * LOG2E; a2[5] = -__expf(al1.y) * LOG2E;
        a2[6] = -__expf(al1.z) * LOG2E; a2[7] = -__expf(al1.w) * LOG2E;
    }
    const float* pdt = dt + (size_t)row0 * DIN + d;
    const float* pu  = u  + (size_t)row0 * DIN + d;
    float h[8], Ap[8];
#pragma unroll
    for (int j = 0; j < 8; j++) { h[j] = 0.f; Ap[j] = 1.f; }

#pragma unroll 4
    for (int t = 0; t < TCH; t++) {
        const float dtv = pdt[t * DIN];
        const float uv  = pu[t * DIN];
        const float du = dtv * uv;
        float bv[8];
        *(float4*)&bv[0] = *(const float4*)&sB[t * NST + nh * 8];
        *(float4*)&bv[4] = *(const float4*)&sB[t * NST + nh * 8 + 4];
#pragma unroll
        for (int j = 0; j < 8; j++) {
            const float e = EXP2F(dtv * a2[j]);
            Ap[j] *= e;
            h[j] = h[j] * e + du * bv[j];
        }
    }
    const size_t idx = (((size_t)bb * CCH + c) * DIN + d) * NST + nh * 8;
    *(float4*)&Aprod[idx]     = make_float4(Ap[0], Ap[1], Ap[2], Ap[3]);
    *(float4*)&Aprod[idx + 4] = make_float4(Ap[4], Ap[5], Ap[6], Ap[7]);
    *(float4*)&Bacc[idx]      = make_float4(h[0], h[1], h[2], h[3]);
    *(float4*)&Bacc[idx + 4]  = make_float4(h[4], h[5], h[6], h[7]);
}

__global__ __launch_bounds__(256) void scan_p2(
    const float* __restrict__ Aprod, const float* __restrict__ Bacc,
    float* __restrict__ hstart)
{
    const int i = blockIdx.x * 256 + threadIdx.x;
    const int bb = i >> 15;          // DIN*NST = 32768 per batch
    const int dn = i & 32767;
    float hs = 0.f;
#pragma unroll
    for (int c = 0; c < CCH; c++) {
        const size_t idx = (((size_t)bb * CCH + c) << 15) + dn;
        hstart[idx] = hs;
        hs = Aprod[idx] * hs + Bacc[idx];
    }
}

__global__ __launch_bounds__(256) void scan_p3(
    const float* __restrict__ dt, const float* __restrict__ u,
    const float* __restrict__ Bm, const float* __restrict__ Cm,
    const float* __restrict__ A_log, const float* __restrict__ Dp,
    const __hip_bfloat16* __restrict__ zs, const float* __restrict__ hstart,
    __hip_bfloat16* __restrict__ y)
{
    __shared__ float sB[TCH * NST], sC[TCH * NST];
    const int blk = blockIdx.x;
    const int bb = blk >> 9, c = (blk >> 4) & 31, dtile = blk & 15;
    const int tid = threadIdx.x;
    const int nh = tid & 1, dl = tid >> 1;
    const int d = dtile * 128 + dl;
    const int row0 = bb * LSEQ + c * TCH;

    sB[tid]       = Bm[(size_t)row0 * NST + tid];
    sB[tid + 256] = Bm[(size_t)row0 * NST + tid + 256];
    sC[tid]       = Cm[(size_t)row0 * NST + tid];
    sC[tid + 256] = Cm[(size_t)row0 * NST + tid + 256];
    __syncthreads();

    float a2[8];
    {
        const float4 al0 = *(const float4*)&A_log[(size_t)d * NST + nh * 8];
        const float4 al1 = *(const float4*)&A_log[(size_t)d * NST + nh * 8 + 4];
        a2[0] = -__expf(al0.x) * LOG2E; a2[1] = -__expf(al0.y) * LOG2E;
        a2[2] = -__expf(al0.z) * LOG2E; a2[3] = -__expf(al0.w) * LOG2E;
        a2[4] = -__expf(al1.x) * LOG2E; a2[5] = -__expf(al1.y) * LOG2E;
        a2[6] = -__expf(al1.z) * LOG2E; a2[7] = -__expf(al1.w) * LOG2E;
    }
    const float Dd = Dp[d];
    const size_t idx = (((size_t)bb * CCH + c) * DIN + d) * NST + nh * 8;
    float h[8];
    *(float4*)&h[0] = *(const float4*)&hstart[idx];
    *(float4*)&h[4] = *(const float4*)&hstart[idx + 4];

    const float* pdt = dt + (size_t)row0 * DIN + d;
    const float* pu  = u  + (size_t)row0 * DIN + d;
    const __hip_bfloat16* pz = zs + (size_t)row0 * DIN + d;
    __hip_bfloat16* py = y + (size_t)row0 * DIN + d;

#pragma unroll 2
    for (int t = 0; t < TCH; t++) {
        const float dtv = pdt[t * DIN];
        const float uv  = pu[t * DIN];
        const float du = dtv * uv;
        float bv[8], cv[8];
        *(float4*)&bv[0] = *(const float4*)&sB[t * NST + nh * 8];
        *(float4*)&bv[4] = *(const float4*)&sB[t * NST + nh * 8 + 4];
        *(float4*)&cv[0] = *(const float4*)&sC[t * NST + nh * 8];
        *(float4*)&cv[4] = *(const float4*)&sC[t * NST + nh * 8 + 4];
        float yp = 0.f;
#pragma unroll
        for (int j = 0; j < 8; j++) {
            const float e = EXP2F(dtv * a2[j]);
            h[j] = h[j] * e + du * bv[j];
            yp += h[j] * cv[j];
        }
        yp += __shfl_xor(yp, 1, 64);
        if (nh == 0) {
            const float zv = __bfloat162float(pz[t * DIN]);
            py[t * DIN] = __float2bfloat16((yp + uv * Dd) * zv);
        }
    }
}

extern "C" void kernel_launch(void* const* d_in, const int* in_sizes, int n_in,
                              void* d_out, int out_size, void* d_ws, size_t ws_size,
                              hipStream_t stream) {
    const float* x      = (const float*)d_in[0];
    const float* ln_g   = (const float*)d_in[1];
    const float* ln_b   = (const float*)d_in[2];
    const float* w_in   = (const float*)d_in[3];   // (4096,1024)
    const float* conv_w = (const float*)d_in[4];   // (2048,1,4)
    const float* conv_b = (const float*)d_in[5];
    const float* dtin_w = (const float*)d_in[6];   // (64,2048)
    const float* dtin_b = (const float*)d_in[7];
    const float* dt_w   = (const float*)d_in[8];   // (2048,64)
    const float* dt_b   = (const float*)d_in[9];
    const float* B_w    = (const float*)d_in[10];  // (16,2048)
    const float* C_w    = (const float*)d_in[11];
    const float* A_log  = (const float*)d_in[12];  // (2048,16)
    const float* Dp     = (const float*)d_in[13];
    const float* out_w  = (const float*)d_in[14];  // (1024,2048)
    float* out = (float*)d_out;

    char* ws = (char*)d_ws;
    auto alloc = [&](size_t bytes) { char* p = ws; ws += (bytes + 255) & ~255ull; return p; };
    __hip_bfloat16* w1b   = (__hip_bfloat16*)alloc((size_t)4096 * 1024 * 2);  // dead after gemm0
    __hip_bfloat16* wpb   = (__hip_bfloat16*)alloc((size_t)96 * 2048 * 2);
    __hip_bfloat16* dtwb  = (__hip_bfloat16*)alloc((size_t)2048 * 64 * 2);
    __hip_bfloat16* owb   = (__hip_bfloat16*)alloc((size_t)1024 * 2048 * 2);
    __hip_bfloat16* xnb   = (__hip_bfloat16*)alloc((size_t)MR * DMOD * 2);
    float*          xproj = (float*)alloc((size_t)MR * DIN * 4);
    __hip_bfloat16* zs    = (__hip_bfloat16*)alloc((size_t)MR * DIN * 2);
    float*          xcf   = (float*)alloc((size_t)MR * DIN * 4);
    __hip_bfloat16* xcb   = (__hip_bfloat16*)alloc((size_t)MR * DIN * 2);
    __hip_bfloat16* dtinb = (__hip_bfloat16*)alloc((size_t)MR * 64 * 2);
    float*          Bmf   = (float*)alloc((size_t)MR * NST * 4);
    float*          Cmf   = (float*)alloc((size_t)MR * NST * 4);
    float*          dtf   = (float*)alloc((size_t)MR * DIN * 4);
    __hip_bfloat16* yb    = (__hip_bfloat16*)alloc((size_t)MR * DIN * 2);
    float*          Aprod = (float*)alloc((size_t)BL * CCH * DIN * NST * 4);
    float*          Bacc  = (float*)alloc((size_t)BL * CCH * DIN * NST * 4);
    float*          hstart= (float*)alloc((size_t)BL * CCH * DIN * NST * 4);
    float*          part  = (float*)w1b;  // split-K partials (6.3MB) alias dead w1b (8MB)

    cvt_all<<<1024, 256, 0, stream>>>(w_in, dtin_w, B_w, C_w, dt_w, out_w, w1b, wpb, dtwb, owb);
    ln_kernel<<<MR, 256, 0, stream>>>(x, ln_g, ln_b, xnb);

    // [x_proj | silu(z)] = ln(x) @ in_proj_w^T : (2048 x 4096), K=1024
    gemm_bt<0><<<dim3(32, 16, 1), 256, 0, stream>>>(xnb, 1024, w1b, 1024, MR, 4096, 1024,
                                                    xproj, zs, nullptr);
    conv_silu_kernel<<<dim3(8, 32), 256, 0, stream>>>(xproj, conv_w, conv_b, xcf, xcb);

    // [dtin|Bm|Cm] partials = x_conv @ [dtin_w;B_w;C_w]^T : (2048 x 96), K=2048, split-K=8
    gemm_bt<1><<<dim3(1, 16, KSPLIT), 256, 0, stream>>>(xcb, 2048, wpb, 2048, MR, 96, 2048 / KSPLIT,
                                                        part, nullptr, nullptr);
    ep1_kernel<<<(MR * 96 + 255) / 256, 256, 0, stream>>>(part, dtin_b, dtinb, Bmf, Cmf);

    // dt = softplus(dtin @ dt_w^T + dt_b) : (2048 x 2048), K=64
    gemm_bt<2><<<dim3(16, 16, 1), 256, 0, stream>>>(dtinb, 64, dtwb, 64, MR, DIN, 64,
                                                    dtf, nullptr, dt_b);

    // chunked selective scan
    scan_p1<<<BL * CCH * 16, 256, 0, stream>>>(dtf, xcf, Bmf, A_log, Aprod, Bacc);
    scan_p2<<<BL * DIN * NST / 256, 256, 0, stream>>>(Aprod, Bacc, hstart);
    scan_p3<<<BL * CCH * 16, 256, 0, stream>>>(dtf, xcf, Bmf, Cmf, A_log, Dp, zs, hstart, yb);

    // out = y @ out_w^T + residual : (2048 x 1024), K=2048
    gemm_bt<3><<<dim3(8, 16, 1), 256, 0, stream>>>(yb, 2048, owb, 2048, MR, DMOD, 2048,
                                                   out, (void*)x, nullptr);
}

// Round 4
// 270.713 us; speedup vs baseline: 3.6610x; 1.0669x over previous
//
#include <hip/hip_runtime.h>
#include <hip/hip_bf16.h>
#include <cstdint>

// ---- problem constants ----
#define BL    2
#define LSEQ  1024
#define DMOD  1024
#define DIN   2048      // inner dim
#define NST   16        // d_state
#define DTRK  64        // dt rank
#define MR    (BL*LSEQ) // 2048 rows

// chunked scan: C chunks of T timesteps
#define CCH 32
#define TCH 32          // LSEQ / CCH
#define KSPLIT 8        // split-K for the thin (N=96) GEMM

typedef __bf16 bf16x8 __attribute__((ext_vector_type(8)));
typedef float  f32x4  __attribute__((ext_vector_type(4)));

#if __has_builtin(__builtin_amdgcn_exp2f)
#define EXP2F(x) __builtin_amdgcn_exp2f(x)
#else
#define EXP2F(x) exp2f(x)
#endif
#define LOG2E 1.4426950408889634f

// async global->LDS, 16B per lane. LDS dest = wave-uniform base + lane*16 (m104).
__device__ __forceinline__ void glds16(const void* g, const void* l) {
    __builtin_amdgcn_global_load_lds(
        (__attribute__((address_space(1))) void*)(uintptr_t)(g),
        (__attribute__((address_space(3))) void*)(uint32_t)(uintptr_t)(l),
        16, 0, 0);
}

// C[M][N] = A[M][K] (bf16,lda) * B[N][K]^T (bf16,ldb), fp32 accum.
// Double-buffered LDS: barrier -> issue next DMAs -> compute current. The DMAs
// are in flight across the whole compute phase, so the compiler's vmcnt(0)
// drain at the next barrier is ~free (fixes the 1740 cyc/k-iter stall at
// 1 block/CU seen in R3).
// XOR swizzle phys_q=(q+(row>>1))&3 spreads ds_read_b128 banks (2-way max = free).
// MODE 0: e0=float* xproj (gn<2048), e1=bf16* zs = silu(acc) (gn>=2048)   [in_proj]
// MODE 1: e0=float* partial[(z*M+gm)*96+gn]                               [dtin/B/C, split-K]
// MODE 2: e0=float* dt = softplus(acc + bias[gn])                         [dt proj]
// MODE 3: e0=float* out = acc + res[gm*N+gn], e1=const float* res         [out proj]
template <int MODE>
__global__ __launch_bounds__(256, 2) void gemm_bt(
    const __hip_bfloat16* __restrict__ A, int lda,
    const __hip_bfloat16* __restrict__ Bw, int ldb,
    int M, int N, int Ksl,
    void* __restrict__ e0, void* __restrict__ e1,
    const float* __restrict__ bias)
{
    __shared__ __align__(16) __hip_bfloat16 sA[2][128 * 32];
    __shared__ __align__(16) __hip_bfloat16 sB[2][128 * 32];

    const int m0 = blockIdx.y * 128;
    const int n0 = blockIdx.x * 128;
    const int k0 = blockIdx.z * Ksl;
    const int tid = threadIdx.x;
    const int w = tid >> 6, lane = tid & 63;
    const int wm = (w >> 1) * 64, wn = (w & 1) * 64;
    const int lrow = lane & 15, lq = lane >> 4;

    // staging map: thread tid stages LDS slot (row=tid>>2, phys_q=tid&3) at byte
    // offset tid*16; the global chunk fetched is logical q = (phys_q - (row>>1))&3.
    // rows +64 have the same swizzle ((row+64)>>1 ≡ row>>1 mod 4).
    const int r0 = tid >> 2;
    const int qs = ((tid & 3) - (r0 >> 1)) & 3;
    const __hip_bfloat16* pa0 = A  + (size_t)(m0 + r0)      * lda + k0 + qs * 8;
    const __hip_bfloat16* pa1 = A  + (size_t)(m0 + r0 + 64) * lda + k0 + qs * 8;
    const __hip_bfloat16* pb0 = Bw + (size_t)(n0 + r0)      * ldb + k0 + qs * 8;
    const __hip_bfloat16* pb1 = Bw + (size_t)(n0 + r0 + 64) * ldb + k0 + qs * 8;
    // NOTE (MODE 1): rows n>=96 of Bw read past the 96-row weight slab into adjacent
    // workspace — finite garbage, columns discarded in epilogue (gn>=N guard).

    f32x4 acc[4][4];
#pragma unroll
    for (int i = 0; i < 4; i++)
#pragma unroll
        for (int j = 0; j < 4; j++) { acc[i][j][0]=0.f; acc[i][j][1]=0.f; acc[i][j][2]=0.f; acc[i][j][3]=0.f; }

    const int nk = Ksl >> 5;
    // prologue: stage k-block 0 into buffer 0
    glds16(pa0, &sA[0][tid * 8]);
    glds16(pa1, &sA[0][2048 + tid * 8]);
    glds16(pb0, &sB[0][tid * 8]);
    glds16(pb1, &sB[0][2048 + tid * 8]);

    for (int kb = 0; kb < nk; ++kb) {
        const int cur = kb & 1, nxt = cur ^ 1;
        __syncthreads();   // drains DMAs for buf cur (in flight since last iter's compute)
        if (kb + 1 < nk) {
            pa0 += 32; pa1 += 32; pb0 += 32; pb1 += 32;
            glds16(pa0, &sA[nxt][tid * 8]);
            glds16(pa1, &sA[nxt][2048 + tid * 8]);
            glds16(pb0, &sB[nxt][tid * 8]);
            glds16(pb1, &sB[nxt][2048 + tid * 8]);
        }
        bf16x8 af[4], bb[4];
#pragma unroll
        for (int mt = 0; mt < 4; mt++) {
            const int row = wm + mt * 16 + lrow;
            af[mt] = *(const bf16x8*)&sA[cur][row * 32 + (((lq + (row >> 1)) & 3) * 8)];
        }
#pragma unroll
        for (int nt = 0; nt < 4; nt++) {
            const int row = wn + nt * 16 + lrow;
            bb[nt] = *(const bf16x8*)&sB[cur][row * 32 + (((lq + (row >> 1)) & 3) * 8)];
        }
#pragma unroll
        for (int mt = 0; mt < 4; mt++)
#pragma unroll
            for (int nt = 0; nt < 4; nt++)
                acc[mt][nt] = __builtin_amdgcn_mfma_f32_16x16x32_bf16(af[mt], bb[nt], acc[mt][nt], 0, 0, 0);
    }

    // epilogue: C[row=(lane>>4)*4+r][col=lane&15]  (m89/m91-verified layout)
#pragma unroll
    for (int mt = 0; mt < 4; mt++) {
#pragma unroll
        for (int nt = 0; nt < 4; nt++) {
            const int gn = n0 + wn + nt * 16 + lrow;
            if (gn >= N) continue;
            const int gmb = m0 + wm + mt * 16 + lq * 4;
#pragma unroll
            for (int r = 0; r < 4; r++) {
                const int gm = gmb + r;
                const float v = acc[mt][nt][r];
                if (MODE == 0) {
                    if (gn < DIN) ((float*)e0)[(size_t)gm * DIN + gn] = v;
                    else {
                        const float s = v / (1.f + __expf(-v));
                        ((__hip_bfloat16*)e1)[(size_t)gm * DIN + (gn - DIN)] = __float2bfloat16(s);
                    }
                } else if (MODE == 1) {
                    ((float*)e0)[((size_t)blockIdx.z * M + gm) * 96 + gn] = v;
                } else if (MODE == 2) {
                    const float xx = v + bias[gn];
                    ((float*)e0)[(size_t)gm * N + gn] = (xx > 20.f) ? xx : log1pf(__expf(xx));
                } else { // MODE 3
                    ((float*)e0)[(size_t)gm * N + gn] = v + ((const float*)e1)[(size_t)gm * N + gn];
                }
            }
        }
    }
}

// reduce split-K partials; emit dtin (bf16, +bias), Bm, Cm (float)
__global__ void ep1_kernel(const float* __restrict__ part, const float* __restrict__ dtin_b,
                           __hip_bfloat16* __restrict__ dtinb, float* __restrict__ Bmf,
                           float* __restrict__ Cmf) {
    const int i = blockIdx.x * 256 + threadIdx.x;
    if (i >= MR * 96) return;
    const int m = i / 96, n = i - m * 96;
    float s = 0.f;
#pragma unroll
    for (int z = 0; z < KSPLIT; z++) s += part[((size_t)z * MR + m) * 96 + n];
    if (n < 64)      dtinb[(size_t)m * 64 + n] = __float2bfloat16(s + dtin_b[n]);
    else if (n < 80) Bmf[(size_t)m * NST + (n - 64)] = s;
    else             Cmf[(size_t)m * NST + (n - 80)] = s;
}

// all weight f32->bf16 conversions in one launch (vec4)
__global__ void cvt_all(const float* __restrict__ w_in, const float* __restrict__ dtin_w,
                        const float* __restrict__ B_w, const float* __restrict__ C_w,
                        const float* __restrict__ dt_w, const float* __restrict__ out_w,
                        __hip_bfloat16* __restrict__ w1b, __hip_bfloat16* __restrict__ wpb,
                        __hip_bfloat16* __restrict__ dtwb, __hip_bfloat16* __restrict__ owb) {
    const int NV = (4194304 + 131072 + 32768 + 32768 + 131072 + 2097152) / 4;
    for (int v = blockIdx.x * 256 + threadIdx.x; v < NV; v += gridDim.x * 256) {
        const int i = v * 4;
        const float* s; __hip_bfloat16* dk;
        if      (i < 4194304) { s = w_in   + i;             dk = w1b  + i; }
        else if (i < 4325376) { s = dtin_w + (i - 4194304); dk = wpb  + (i - 4194304); }
        else if (i < 4358144) { s = B_w    + (i - 4325376); dk = wpb  + 131072 + (i - 4325376); }
        else if (i < 4390912) { s = C_w    + (i - 4358144); dk = wpb  + 163840 + (i - 4358144); }
        else if (i < 4521984) { s = dt_w   + (i - 4390912); dk = dtwb + (i - 4390912); }
        else                  { s = out_w  + (i - 4521984); dk = owb  + (i - 4521984); }
        const float4 f = *(const float4*)s;
        __hip_bfloat16 t0 = __float2bfloat16(f.x), t1 = __float2bfloat16(f.y);
        __hip_bfloat16 t2 = __float2bfloat16(f.z), t3 = __float2bfloat16(f.w);
        ushort4 o;
        o.x = *(unsigned short*)&t0; o.y = *(unsigned short*)&t1;
        o.z = *(unsigned short*)&t2; o.w = *(unsigned short*)&t3;
        *(ushort4*)dk = o;
    }
}

__global__ void ln_kernel(const float* __restrict__ x, const float* __restrict__ g,
                          const float* __restrict__ b, __hip_bfloat16* __restrict__ xn) {
    const int row = blockIdx.x;
    const int tid = threadIdx.x;
    const float4 v = ((const float4*)(x + (size_t)row * DMOD))[tid];
    float s  = v.x + v.y + v.z + v.w;
    float sq = v.x * v.x + v.y * v.y + v.z * v.z + v.w * v.w;
#pragma unroll
    for (int off = 32; off >= 1; off >>= 1) {
        s  += __shfl_down(s, off, 64);
        sq += __shfl_down(sq, off, 64);
    }
    __shared__ float red[8];
    const int w = tid >> 6, lane = tid & 63;
    if (lane == 0) { red[w] = s; red[4 + w] = sq; }
    __syncthreads();
    s  = red[0] + red[1] + red[2] + red[3];
    sq = red[4] + red[5] + red[6] + red[7];
    const float mean = s * (1.f / DMOD);
    const float rstd = rsqrtf(sq * (1.f / DMOD) - mean * mean + 1e-5f);
    const int col = tid * 4;
    const float vv[4] = {v.x, v.y, v.z, v.w};
#pragma unroll
    for (int i = 0; i < 4; i++)
        xn[(size_t)row * DMOD + col + i] =
            __float2bfloat16((vv[i] - mean) * rstd * g[col + i] + b[col + i]);
}

// causal depthwise conv(4) + silu over x_proj (2048 x 2048 float), rolling registers.
// grid: (8 d-tiles of 256, 32 m-ranges of 64). 64|1024 so ranges never straddle batches.
// emits bf16 only (scan consumes u in bf16; saves 16MB wr + 32MB rd of float copy).
__global__ void conv_silu_kernel(const float* __restrict__ xp, const float* __restrict__ cw,
                                 const float* __restrict__ cb,
                                 __hip_bfloat16* __restrict__ xcb) {
    const int d = blockIdx.x * 256 + threadIdx.x;
    const int m0 = blockIdx.y * 64;
    const int l0 = m0 & (LSEQ - 1);
    const float w0 = cw[d * 4], w1 = cw[d * 4 + 1], w2 = cw[d * 4 + 2], w3 = cw[d * 4 + 3];
    const float cbd = cb[d];
    float x0 = 0.f, x1 = 0.f, x2 = 0.f;
    if (l0 != 0) {
        x0 = xp[(size_t)(m0 - 3) * DIN + d];
        x1 = xp[(size_t)(m0 - 2) * DIN + d];
        x2 = xp[(size_t)(m0 - 1) * DIN + d];
    }
#pragma unroll 4
    for (int i = 0; i < 64; i++) {
        const float x3 = xp[(size_t)(m0 + i) * DIN + d];
        const float a = cbd + w0 * x0 + w1 * x1 + w2 * x2 + w3 * x3;
        const float sv = a / (1.f + __expf(-a));
        xcb[(size_t)(m0 + i) * DIN + d] = __float2bfloat16(sv);
        x0 = x1; x1 = x2; x2 = x3;
    }
}

// ===================== chunked selective scan =====================
// thread = (b, d, n-half, chunk): 8 h-states in registers, no shuffle tree.
// block: 256 thr = 128 d x 2 nh, one chunk. grid decode: blk = ((bb*32+c)*16+dtile)

__global__ __launch_bounds__(256) void scan_p1(
    const float* __restrict__ dt, const __hip_bfloat16* __restrict__ u,
    const float* __restrict__ Bm, const float* __restrict__ A_log,
    float* __restrict__ Aprod, float* __restrict__ Bacc)
{
    __shared__ float sB[TCH * NST];
    const int blk = blockIdx.x;
    const int bb = blk >> 9, c = (blk >> 4) & 31, dtile = blk & 15;
    const int tid = threadIdx.x;
    const int nh = tid & 1, dl = tid >> 1;
    const int d = dtile * 128 + dl;
    const int row0 = bb * LSEQ + c * TCH;

    sB[tid]       = Bm[(size_t)row0 * NST + tid];
    sB[tid + 256] = Bm[(size_t)row0 * NST + tid + 256];
    __syncthreads();

    float a2[8];
    {
        const float4 al0 = *(const float4*)&A_log[(size_t)d * NST + nh * 8];
        const float4 al1 = *(const float4*)&A_log[(size_t)d * NST + nh * 8 + 4];
        a2[0] = -__expf(al0.x) * LOG2E; a2[1] = -__expf(al0.y) * LOG2E;
        a2[2] = -__expf(al0.z) * LOG2E; a2[3] = -__expf(al0.w) * LOG2E;
        a2[4] = -__expf(al1.x) * LOG2E; a2[5] = -__expf(al1.y) * LOG2E;
        a2[6] = -__expf(al1.z) * LOG2E; a2[7] = -__expf(al1.w) * LOG2E;
    }
    const float* pdt = dt + (size_t)row0 * DIN + d;
    const __hip_bfloat16* pu = u + (size_t)row0 * DIN + d;
    float h[8], Ap[8];
#pragma unroll
    for (int j = 0; j < 8; j++) { h[j] = 0.f; Ap[j] = 1.f; }

#pragma unroll 4
    for (int t = 0; t < TCH; t++) {
        const float dtv = pdt[t * DIN];
        const float uv  = __bfloat162float(pu[t * DIN]);
        const float du = dtv * uv;
        float bv[8];
        *(float4*)&bv[0] = *(const float4*)&sB[t * NST + nh * 8];
        *(float4*)&bv[4] = *(const float4*)&sB[t * NST + nh * 8 + 4];
#pragma unroll
        for (int j = 0; j < 8; j++) {
            const float e = EXP2F(dtv * a2[j]);
            Ap[j] *= e;
            h[j] = h[j] * e + du * bv[j];
        }
    }
    const size_t idx = (((size_t)bb * CCH + c) * DIN + d) * NST + nh * 8;
    *(float4*)&Aprod[idx]     = make_float4(Ap[0], Ap[1], Ap[2], Ap[3]);
    *(float4*)&Aprod[idx + 4] = make_float4(Ap[4], Ap[5], Ap[6], Ap[7]);
    *(float4*)&Bacc[idx]      = make_float4(h[0], h[1], h[2], h[3]);
    *(float4*)&Bacc[idx + 4]  = make_float4(h[4], h[5], h[6], h[7]);
}

__global__ __launch_bounds__(256) void scan_p2(
    const float* __restrict__ Aprod, const float* __restrict__ Bacc,
    float* __restrict__ hstart)
{
    const int i = blockIdx.x * 256 + threadIdx.x;
    const int bb = i >> 15;          // DIN*NST = 32768 per batch
    const int dn = i & 32767;
    float hs = 0.f;
#pragma unroll
    for (int c = 0; c < CCH; c++) {
        const size_t idx = (((size_t)bb * CCH + c) << 15) + dn;
        hstart[idx] = hs;
        hs = Aprod[idx] * hs + Bacc[idx];
    }
}

__global__ __launch_bounds__(256) void scan_p3(
    const float* __restrict__ dt, const __hip_bfloat16* __restrict__ u,
    const float* __restrict__ Bm, const float* __restrict__ Cm,
    const float* __restrict__ A_log, const float* __restrict__ Dp,
    const __hip_bfloat16* __restrict__ zs, const float* __restrict__ hstart,
    __hip_bfloat16* __restrict__ y)
{
    __shared__ float sB[TCH * NST], sC[TCH * NST];
    const int blk = blockIdx.x;
    const int bb = blk >> 9, c = (blk >> 4) & 31, dtile = blk & 15;
    const int tid = threadIdx.x;
    const int nh = tid & 1, dl = tid >> 1;
    const int d = dtile * 128 + dl;
    const int row0 = bb * LSEQ + c * TCH;

    sB[tid]       = Bm[(size_t)row0 * NST + tid];
    sB[tid + 256] = Bm[(size_t)row0 * NST + tid + 256];
    sC[tid]       = Cm[(size_t)row0 * NST + tid];
    sC[tid + 256] = Cm[(size_t)row0 * NST + tid + 256];
    __syncthreads();

    float a2[8];
    {
        const float4 al0 = *(const float4*)&A_log[(size_t)d * NST + nh * 8];
        const float4 al1 = *(const float4*)&A_log[(size_t)d * NST + nh * 8 + 4];
        a2[0] = -__expf(al0.x) * LOG2E; a2[1] = -__expf(al0.y) * LOG2E;
        a2[2] = -__expf(al0.z) * LOG2E; a2[3] = -__expf(al0.w) * LOG2E;
        a2[4] = -__expf(al1.x) * LOG2E; a2[5] = -__expf(al1.y) * LOG2E;
        a2[6] = -__expf(al1.z) * LOG2E; a2[7] = -__expf(al1.w) * LOG2E;
    }
    const float Dd = Dp[d];
    const size_t idx = (((size_t)bb * CCH + c) * DIN + d) * NST + nh * 8;
    float h[8];
    *(float4*)&h[0] = *(const float4*)&hstart[idx];
    *(float4*)&h[4] = *(const float4*)&hstart[idx + 4];

    const float* pdt = dt + (size_t)row0 * DIN + d;
    const __hip_bfloat16* pu = u + (size_t)row0 * DIN + d;
    const __hip_bfloat16* pz = zs + (size_t)row0 * DIN + d;
    __hip_bfloat16* py = y + (size_t)row0 * DIN + d;

#pragma unroll 2
    for (int t = 0; t < TCH; t++) {
        const float dtv = pdt[t * DIN];
        const float uv  = __bfloat162float(pu[t * DIN]);
        const float du = dtv * uv;
        float bv[8], cv[8];
        *(float4*)&bv[0] = *(const float4*)&sB[t * NST + nh * 8];
        *(float4*)&bv[4] = *(const float4*)&sB[t * NST + nh * 8 + 4];
        *(float4*)&cv[0] = *(const float4*)&sC[t * NST + nh * 8];
        *(float4*)&cv[4] = *(const float4*)&sC[t * NST + nh * 8 + 4];
        float yp = 0.f;
#pragma unroll
        for (int j = 0; j < 8; j++) {
            const float e = EXP2F(dtv * a2[j]);
            h[j] = h[j] * e + du * bv[j];
            yp += h[j] * cv[j];
        }
        yp += __shfl_xor(yp, 1, 64);
        if (nh == 0) {
            const float zv = __bfloat162float(pz[t * DIN]);
            py[t * DIN] = __float2bfloat16((yp + uv * Dd) * zv);
        }
    }
}

extern "C" void kernel_launch(void* const* d_in, const int* in_sizes, int n_in,
                              void* d_out, int out_size, void* d_ws, size_t ws_size,
                              hipStream_t stream) {
    const float* x      = (const float*)d_in[0];
    const float* ln_g   = (const float*)d_in[1];
    const float* ln_b   = (const float*)d_in[2];
    const float* w_in   = (const float*)d_in[3];   // (4096,1024)
    const float* conv_w = (const float*)d_in[4];   // (2048,1,4)
    const float* conv_b = (const float*)d_in[5];
    const float* dtin_w = (const float*)d_in[6];   // (64,2048)
    const float* dtin_b = (const float*)d_in[7];
    const float* dt_w   = (const float*)d_in[8];   // (2048,64)
    const float* dt_b   = (const float*)d_in[9];
    const float* B_w    = (const float*)d_in[10];  // (16,2048)
    const float* C_w    = (const float*)d_in[11];
    const float* A_log  = (const float*)d_in[12];  // (2048,16)
    const float* Dp     = (const float*)d_in[13];
    const float* out_w  = (const float*)d_in[14];  // (1024,2048)
    float* out = (float*)d_out;

    char* ws = (char*)d_ws;
    auto alloc = [&](size_t bytes) { char* p = ws; ws += (bytes + 255) & ~255ull; return p; };
    __hip_bfloat16* w1b   = (__hip_bfloat16*)alloc((size_t)4096 * 1024 * 2);  // dead after gemm0
    __hip_bfloat16* wpb   = (__hip_bfloat16*)alloc((size_t)96 * 2048 * 2);
    __hip_bfloat16* dtwb  = (__hip_bfloat16*)alloc((size_t)2048 * 64 * 2);
    __hip_bfloat16* owb   = (__hip_bfloat16*)alloc((size_t)1024 * 2048 * 2);
    __hip_bfloat16* xnb   = (__hip_bfloat16*)alloc((size_t)MR * DMOD * 2);
    float*          xproj = (float*)alloc((size_t)MR * DIN * 4);
    __hip_bfloat16* zs    = (__hip_bfloat16*)alloc((size_t)MR * DIN * 2);
    __hip_bfloat16* xcb   = (__hip_bfloat16*)alloc((size_t)MR * DIN * 2);
    __hip_bfloat16* dtinb = (__hip_bfloat16*)alloc((size_t)MR * 64 * 2);
    float*          Bmf   = (float*)alloc((size_t)MR * NST * 4);
    float*          Cmf   = (float*)alloc((size_t)MR * NST * 4);
    float*          dtf   = (float*)alloc((size_t)MR * DIN * 4);
    __hip_bfloat16* yb    = (__hip_bfloat16*)alloc((size_t)MR * DIN * 2);
    float*          Aprod = (float*)alloc((size_t)BL * CCH * DIN * NST * 4);
    float*          Bacc  = (float*)alloc((size_t)BL * CCH * DIN * NST * 4);
    float*          hstart= (float*)alloc((size_t)BL * CCH * DIN * NST * 4);
    float*          part  = (float*)w1b;  // split-K partials (6.3MB) alias dead w1b (8MB)

    cvt_all<<<1024, 256, 0, stream>>>(w_in, dtin_w, B_w, C_w, dt_w, out_w, w1b, wpb, dtwb, owb);
    ln_kernel<<<MR, 256, 0, stream>>>(x, ln_g, ln_b, xnb);

    // [x_proj | silu(z)] = ln(x) @ in_proj_w^T : (2048 x 4096), K=1024
    gemm_bt<0><<<dim3(32, 16, 1), 256, 0, stream>>>(xnb, 1024, w1b, 1024, MR, 4096, 1024,
                                                    xproj, zs, nullptr);
    conv_silu_kernel<<<dim3(8, 32), 256, 0, stream>>>(xproj, conv_w, conv_b, xcb);

    // [dtin|Bm|Cm] partials = x_conv @ [dtin_w;B_w;C_w]^T : (2048 x 96), K=2048, split-K=8
    gemm_bt<1><<<dim3(1, 16, KSPLIT), 256, 0, stream>>>(xcb, 2048, wpb, 2048, MR, 96, 2048 / KSPLIT,
                                                        part, nullptr, nullptr);
    ep1_kernel<<<(MR * 96 + 255) / 256, 256, 0, stream>>>(part, dtin_b, dtinb, Bmf, Cmf);

    // dt = softplus(dtin @ dt_w^T + dt_b) : (2048 x 2048), K=64
    gemm_bt<2><<<dim3(16, 16, 1), 256, 0, stream>>>(dtinb, 64, dtwb, 64, MR, DIN, 64,
                                                    dtf, nullptr, dt_b);

    // chunked selective scan
    scan_p1<<<BL * CCH * 16, 256, 0, stream>>>(dtf, xcb, Bmf, A_log, Aprod, Bacc);
    scan_p2<<<BL * DIN * NST / 256, 256, 0, stream>>>(Aprod, Bacc, hstart);
    scan_p3<<<BL * CCH * 16, 256, 0, stream>>>(dtf, xcb, Bmf, Cmf, A_log, Dp, zs, hstart, yb);

    // out = y @ out_w^T + residual : (2048 x 1024), K=2048
    gemm_bt<3><<<dim3(8, 16, 1), 256, 0, stream>>>(yb, 2048, owb, 2048, MR, DMOD, 2048,
                                                   out, (void*)x, nullptr);
}

// Round 5
// 253.867 us; speedup vs baseline: 3.9039x; 1.0664x over previous
//
#include <hip/hip_runtime.h>
#include <hip/hip_bf16.h>
#include <cstdint>

// ---- problem constants ----
#define BL    2
#define LSEQ  1024
#define DMOD  1024
#define DIN   2048      // inner dim
#define NST   16        // d_state
#define DTRK  64        // dt rank
#define MR    (BL*LSEQ) // 2048 rows

// chunked scan: C chunks of T timesteps
#define CCH 32
#define TCH 32          // LSEQ / CCH
#define KSPLIT 8        // split-K for the thin (N=96) GEMM

typedef __bf16 bf16x8 __attribute__((ext_vector_type(8)));
typedef float  f32x4  __attribute__((ext_vector_type(4)));

#if __has_builtin(__builtin_amdgcn_exp2f)
#define EXP2F(x) __builtin_amdgcn_exp2f(x)
#else
#define EXP2F(x) exp2f(x)
#endif
#define LOG2E 1.4426950408889634f

// async global->LDS, 16B per lane. LDS dest = wave-uniform base + lane*16 (m104).
__device__ __forceinline__ void glds16(const void* g, const void* l) {
    __builtin_amdgcn_global_load_lds(
        (__attribute__((address_space(1))) void*)(uintptr_t)(g),
        (__attribute__((address_space(3))) void*)(uint32_t)(uintptr_t)(l),
        16, 0, 0);
}

// C[M][N] = A[M][K] (bf16,lda) * B[N][K]^T (bf16,ldb), fp32 accum.
// TM x TN block tile, 256 threads = 4 waves in 2x2, wave tile (TM/2)x(TN/2).
// TM=64 -> 8-24KB LDS dbuf, 4+ blocks/CU: other blocks' compute hides each
// block's vmcnt(0) barrier drain (m114 wave-overlap mechanism).
// XOR swizzle phys_q=(q+(row>>1))&3 keeps ds_read_b128 at <=2-way bank alias (free).
// XCD-aware block swizzle: same m-band (A-tile) stays on one XCD's L2.
// MODE 0: e0=bf16* xproj (gn<2048), e1=bf16* zs = silu(acc) (gn>=2048)    [in_proj]
// MODE 1: e0=float* partial[(z*M+gm)*96+gn]                               [dtin/B/C, split-K]
// MODE 2: e0=float* dt = softplus(acc + bias[gn])                         [dt proj]
// MODE 3: e0=float* out = acc + res[gm*N+gn], e1=const float* res         [out proj]
template <int MODE, int TM, int TN>
__global__ __launch_bounds__(256, 4) void gemm_bt(
    const __hip_bfloat16* __restrict__ A, int lda,
    const __hip_bfloat16* __restrict__ Bw, int ldb,
    int M, int N, int Ksl,
    void* __restrict__ e0, void* __restrict__ e1,
    const float* __restrict__ bias)
{
    constexpr int WM = TM / 2, WN = TN / 2;
    constexpr int MT = WM / 16, NT = WN / 16;
    constexpr int NDA = TM / 64, NDB = TN / 64;   // 4KB DMA instructions per buffer
    __shared__ __align__(16) __hip_bfloat16 sA[2][TM * 32];
    __shared__ __align__(16) __hip_bfloat16 sB[2][TN * 32];

    // XCD-aware swizzle: blocks on one XCD (bid%8) share the same few m-bands.
    int bx = blockIdx.x, by = blockIdx.y;
    if ((gridDim.y & 7) == 0) {
        const int bid = blockIdx.x + gridDim.x * blockIdx.y;
        const int xcd = bid & 7, s = bid >> 3;
        bx = s % gridDim.x;
        by = (s / gridDim.x) * 8 + xcd;
    }
    const int m0 = by * TM;
    const int n0 = bx * TN;
    const int k0 = blockIdx.z * Ksl;
    const int tid = threadIdx.x;
    const int w = tid >> 6, lane = tid & 63;
    const int wm = (w >> 1) * WM, wn = (w & 1) * WN;
    const int lrow = lane & 15, lq = lane >> 4;

    // staging: thread stages 16B at slot (row=r0+64i, phys_q=tid&3); fetches
    // logical k-chunk qs=(phys_q-(r0>>1))&3 (XOR swizzle; (r0+64i)>>1 ≡ r0>>1 mod 4).
    const int r0 = tid >> 2;
    const int qs = ((tid & 3) - (r0 >> 1)) & 3;
    const __hip_bfloat16* pa[NDA];
    const __hip_bfloat16* pb[NDB];
#pragma unroll
    for (int i = 0; i < NDA; i++) pa[i] = A + (size_t)(m0 + r0 + 64 * i) * lda + k0 + qs * 8;
#pragma unroll
    for (int i = 0; i < NDB; i++) pb[i] = Bw + (size_t)(n0 + r0 + 64 * i) * ldb + k0 + qs * 8;
    // NOTE (MODE 1): rows n>=96 of Bw read past the 96-row weight slab into adjacent
    // workspace — finite garbage, columns discarded in epilogue (gn>=N guard).

    f32x4 acc[MT][NT];
#pragma unroll
    for (int i = 0; i < MT; i++)
#pragma unroll
        for (int j = 0; j < NT; j++) { acc[i][j][0]=0.f; acc[i][j][1]=0.f; acc[i][j][2]=0.f; acc[i][j][3]=0.f; }

    const int nk = Ksl >> 5;
    // prologue: stage k-block 0 into buffer 0
#pragma unroll
    for (int i = 0; i < NDA; i++) glds16(pa[i], &sA[0][i * 2048 + tid * 8]);
#pragma unroll
    for (int i = 0; i < NDB; i++) glds16(pb[i], &sB[0][i * 2048 + tid * 8]);

    for (int kb = 0; kb < nk; ++kb) {
        const int cur = kb & 1, nxt = cur ^ 1;
        __syncthreads();   // drains DMAs for buf cur (in flight since last iter's compute)
        if (kb + 1 < nk) {
#pragma unroll
            for (int i = 0; i < NDA; i++) { pa[i] += 32; glds16(pa[i], &sA[nxt][i * 2048 + tid * 8]); }
#pragma unroll
            for (int i = 0; i < NDB; i++) { pb[i] += 32; glds16(pb[i], &sB[nxt][i * 2048 + tid * 8]); }
        }
        bf16x8 af[MT], bb[NT];
#pragma unroll
        for (int mt = 0; mt < MT; mt++) {
            const int row = wm + mt * 16 + lrow;
            af[mt] = *(const bf16x8*)&sA[cur][row * 32 + (((lq + (row >> 1)) & 3) * 8)];
        }
#pragma unroll
        for (int nt = 0; nt < NT; nt++) {
            const int row = wn + nt * 16 + lrow;
            bb[nt] = *(const bf16x8*)&sB[cur][row * 32 + (((lq + (row >> 1)) & 3) * 8)];
        }
#pragma unroll
        for (int mt = 0; mt < MT; mt++)
#pragma unroll
            for (int nt = 0; nt < NT; nt++)
                acc[mt][nt] = __builtin_amdgcn_mfma_f32_16x16x32_bf16(af[mt], bb[nt], acc[mt][nt], 0, 0, 0);
    }

    // epilogue: C[row=(lane>>4)*4+r][col=lane&15]  (m89/m91-verified layout)
#pragma unroll
    for (int mt = 0; mt < MT; mt++) {
#pragma unroll
        for (int nt = 0; nt < NT; nt++) {
            const int gn = n0 + wn + nt * 16 + lrow;
            if (gn >= N) continue;
            const int gmb = m0 + wm + mt * 16 + lq * 4;
#pragma unroll
            for (int r = 0; r < 4; r++) {
                const int gm = gmb + r;
                const float v = acc[mt][nt][r];
                if (MODE == 0) {
                    if (gn < DIN) ((__hip_bfloat16*)e0)[(size_t)gm * DIN + gn] = __float2bfloat16(v);
                    else {
                        const float s = v / (1.f + __expf(-v));
                        ((__hip_bfloat16*)e1)[(size_t)gm * DIN + (gn - DIN)] = __float2bfloat16(s);
                    }
                } else if (MODE == 1) {
                    ((float*)e0)[((size_t)blockIdx.z * M + gm) * 96 + gn] = v;
                } else if (MODE == 2) {
                    const float xx = v + bias[gn];
                    ((float*)e0)[(size_t)gm * N + gn] = (xx > 20.f) ? xx : log1pf(__expf(xx));
                } else { // MODE 3
                    ((float*)e0)[(size_t)gm * N + gn] = v + ((const float*)e1)[(size_t)gm * N + gn];
                }
            }
        }
    }
}

// reduce split-K partials; emit dtin (bf16, +bias), Bm, Cm (float)
__global__ void ep1_kernel(const float* __restrict__ part, const float* __restrict__ dtin_b,
                           __hip_bfloat16* __restrict__ dtinb, float* __restrict__ Bmf,
                           float* __restrict__ Cmf) {
    const int i = blockIdx.x * 256 + threadIdx.x;
    if (i >= MR * 96) return;
    const int m = i / 96, n = i - m * 96;
    float s = 0.f;
#pragma unroll
    for (int z = 0; z < KSPLIT; z++) s += part[((size_t)z * MR + m) * 96 + n];
    if (n < 64)      dtinb[(size_t)m * 64 + n] = __float2bfloat16(s + dtin_b[n]);
    else if (n < 80) Bmf[(size_t)m * NST + (n - 64)] = s;
    else             Cmf[(size_t)m * NST + (n - 80)] = s;
}

// all weight f32->bf16 conversions in one launch (vec4)
__global__ void cvt_all(const float* __restrict__ w_in, const float* __restrict__ dtin_w,
                        const float* __restrict__ B_w, const float* __restrict__ C_w,
                        const float* __restrict__ dt_w, const float* __restrict__ out_w,
                        __hip_bfloat16* __restrict__ w1b, __hip_bfloat16* __restrict__ wpb,
                        __hip_bfloat16* __restrict__ dtwb, __hip_bfloat16* __restrict__ owb) {
    const int NV = (4194304 + 131072 + 32768 + 32768 + 131072 + 2097152) / 4;
    for (int v = blockIdx.x * 256 + threadIdx.x; v < NV; v += gridDim.x * 256) {
        const int i = v * 4;
        const float* s; __hip_bfloat16* dk;
        if      (i < 4194304) { s = w_in   + i;             dk = w1b  + i; }
        else if (i < 4325376) { s = dtin_w + (i - 4194304); dk = wpb  + (i - 4194304); }
        else if (i < 4358144) { s = B_w    + (i - 4325376); dk = wpb  + 131072 + (i - 4325376); }
        else if (i < 4390912) { s = C_w    + (i - 4358144); dk = wpb  + 163840 + (i - 4358144); }
        else if (i < 4521984) { s = dt_w   + (i - 4390912); dk = dtwb + (i - 4390912); }
        else                  { s = out_w  + (i - 4521984); dk = owb  + (i - 4521984); }
        const float4 f = *(const float4*)s;
        __hip_bfloat16 t0 = __float2bfloat16(f.x), t1 = __float2bfloat16(f.y);
        __hip_bfloat16 t2 = __float2bfloat16(f.z), t3 = __float2bfloat16(f.w);
        ushort4 o;
        o.x = *(unsigned short*)&t0; o.y = *(unsigned short*)&t1;
        o.z = *(unsigned short*)&t2; o.w = *(unsigned short*)&t3;
        *(ushort4*)dk = o;
    }
}

__global__ void ln_kernel(const float* __restrict__ x, const float* __restrict__ g,
                          const float* __restrict__ b, __hip_bfloat16* __restrict__ xn) {
    const int row = blockIdx.x;
    const int tid = threadIdx.x;
    const float4 v = ((const float4*)(x + (size_t)row * DMOD))[tid];
    float s  = v.x + v.y + v.z + v.w;
    float sq = v.x * v.x + v.y * v.y + v.z * v.z + v.w * v.w;
#pragma unroll
    for (int off = 32; off >= 1; off >>= 1) {
        s  += __shfl_down(s, off, 64);
        sq += __shfl_down(sq, off, 64);
    }
    __shared__ float red[8];
    const int w = tid >> 6, lane = tid & 63;
    if (lane == 0) { red[w] = s; red[4 + w] = sq; }
    __syncthreads();
    s  = red[0] + red[1] + red[2] + red[3];
    sq = red[4] + red[5] + red[6] + red[7];
    const float mean = s * (1.f / DMOD);
    const float rstd = rsqrtf(sq * (1.f / DMOD) - mean * mean + 1e-5f);
    const int col = tid * 4;
    const float vv[4] = {v.x, v.y, v.z, v.w};
#pragma unroll
    for (int i = 0; i < 4; i++)
        xn[(size_t)row * DMOD + col + i] =
            __float2bfloat16((vv[i] - mean) * rstd * g[col + i] + b[col + i]);
}

// causal depthwise conv(4) + silu over x_proj (2048 x 2048 bf16), rolling registers.
// grid: (8 d-tiles of 256, 32 m-ranges of 64). 64|1024 so ranges never straddle batches.
__global__ void conv_silu_kernel(const __hip_bfloat16* __restrict__ xp, const float* __restrict__ cw,
                                 const float* __restrict__ cb,
                                 __hip_bfloat16* __restrict__ xcb) {
    const int d = blockIdx.x * 256 + threadIdx.x;
    const int m0 = blockIdx.y * 64;
    const int l0 = m0 & (LSEQ - 1);
    const float w0 = cw[d * 4], w1 = cw[d * 4 + 1], w2 = cw[d * 4 + 2], w3 = cw[d * 4 + 3];
    const float cbd = cb[d];
    float x0 = 0.f, x1 = 0.f, x2 = 0.f;
    if (l0 != 0) {
        x0 = __bfloat162float(xp[(size_t)(m0 - 3) * DIN + d]);
        x1 = __bfloat162float(xp[(size_t)(m0 - 2) * DIN + d]);
        x2 = __bfloat162float(xp[(size_t)(m0 - 1) * DIN + d]);
    }
#pragma unroll 4
    for (int i = 0; i < 64; i++) {
        const float x3 = __bfloat162float(xp[(size_t)(m0 + i) * DIN + d]);
        const float a = cbd + w0 * x0 + w1 * x1 + w2 * x2 + w3 * x3;
        const float sv = a / (1.f + __expf(-a));
        xcb[(size_t)(m0 + i) * DIN + d] = __float2bfloat16(sv);
        x0 = x1; x1 = x2; x2 = x3;
    }
}

// ===================== chunked selective scan =====================
// thread = (b, d, n-half, chunk): 8 h-states in registers, no shuffle tree.
// block: 256 thr = 128 d x 2 nh, one chunk. grid decode: blk = ((bb*32+c)*16+dtile)

__global__ __launch_bounds__(256) void scan_p1(
    const float* __restrict__ dt, const __hip_bfloat16* __restrict__ u,
    const float* __restrict__ Bm, const float* __restrict__ A_log,
    float* __restrict__ Aprod, float* __restrict__ Bacc)
{
    __shared__ float sB[TCH * NST];
    const int blk = blockIdx.x;
    const int bb = blk >> 9, c = (blk >> 4) & 31, dtile = blk & 15;
    const int tid = threadIdx.x;
    const int nh = tid & 1, dl = tid >> 1;
    const int d = dtile * 128 + dl;
    const int row0 = bb * LSEQ + c * TCH;

    sB[tid]       = Bm[(size_t)row0 * NST + tid];
    sB[tid + 256] = Bm[(size_t)row0 * NST + tid + 256];
    __syncthreads();

    float a2[8];
    {
        const float4 al0 = *(const float4*)&A_log[(size_t)d * NST + nh * 8];
        const float4 al1 = *(const float4*)&A_log[(size_t)d * NST + nh * 8 + 4];
        a2[0] = -__expf(al0.x) * LOG2E; a2[1] = -__expf(al0.y) * LOG2E;
        a2[2] = -__expf(al0.z) * LOG2E; a2[3] = -__expf(al0.w) * LOG2E;
        a2[4] = -__expf(al1.x) * LOG2E; a2[5] = -__expf(al1.y) * LOG2E;
        a2[6] = -__expf(al1.z) * LOG2E; a2[7] = -__expf(al1.w) * LOG2E;
    }
    const float* pdt = dt + (size_t)row0 * DIN + d;
    const __hip_bfloat16* pu = u + (size_t)row0 * DIN + d;
    float h[8], Ap[8];
#pragma unroll
    for (int j = 0; j < 8; j++) { h[j] = 0.f; Ap[j] = 1.f; }

#pragma unroll 4
    for (int t = 0; t < TCH; t++) {
        const float dtv = pdt[t * DIN];
        const float uv  = __bfloat162float(pu[t * DIN]);
        const float du = dtv * uv;
        float bv[8];
        *(float4*)&bv[0] = *(const float4*)&sB[t * NST + nh * 8];
        *(float4*)&bv[4] = *(const float4*)&sB[t * NST + nh * 8 + 4];
#pragma unroll
        for (int j = 0; j < 8; j++) {
            const float e = EXP2F(dtv * a2[j]);
            Ap[j] *= e;
            h[j] = h[j] * e + du * bv[j];
        }
    }
    const size_t idx = (((size_t)bb * CCH + c) * DIN + d) * NST + nh * 8;
    *(float4*)&Aprod[idx]     = make_float4(Ap[0], Ap[1], Ap[2], Ap[3]);
    *(float4*)&Aprod[idx + 4] = make_float4(Ap[4], Ap[5], Ap[6], Ap[7]);
    *(float4*)&Bacc[idx]      = make_float4(h[0], h[1], h[2], h[3]);
    *(float4*)&Bacc[idx + 4]  = make_float4(h[4], h[5], h[6], h[7]);
}

__global__ __launch_bounds__(256) void scan_p2(
    const float* __restrict__ Aprod, const float* __restrict__ Bacc,
    float* __restrict__ hstart)
{
    const int i = blockIdx.x * 256 + threadIdx.x;
    const int bb = i >> 15;          // DIN*NST = 32768 per batch
    const int dn = i & 32767;
    float hs = 0.f;
#pragma unroll
    for (int c = 0; c < CCH; c++) {
        const size_t idx = (((size_t)bb * CCH + c) << 15) + dn;
        hstart[idx] = hs;
        hs = Aprod[idx] * hs + Bacc[idx];
    }
}

__global__ __launch_bounds__(256) void scan_p3(
    const float* __restrict__ dt, const __hip_bfloat16* __restrict__ u,
    const float* __restrict__ Bm, const float* __restrict__ Cm,
    const float* __restrict__ A_log, const float* __restrict__ Dp,
    const __hip_bfloat16* __restrict__ zs, const float* __restrict__ hstart,
    __hip_bfloat16* __restrict__ y)
{
    __shared__ float sB[TCH * NST], sC[TCH * NST];
    const int blk = blockIdx.x;
    const int bb = blk >> 9, c = (blk >> 4) & 31, dtile = blk & 15;
    const int tid = threadIdx.x;
    const int nh = tid & 1, dl = tid >> 1;
    const int d = dtile * 128 + dl;
    const int row0 = bb * LSEQ + c * TCH;

    sB[tid]       = Bm[(size_t)row0 * NST + tid];
    sB[tid + 256] = Bm[(size_t)row0 * NST + tid + 256];
    sC[tid]       = Cm[(size_t)row0 * NST + tid];
    sC[tid + 256] = Cm[(size_t)row0 * NST + tid + 256];
    __syncthreads();

    float a2[8];
    {
        const float4 al0 = *(const float4*)&A_log[(size_t)d * NST + nh * 8];
        const float4 al1 = *(const float4*)&A_log[(size_t)d * NST + nh * 8 + 4];
        a2[0] = -__expf(al0.x) * LOG2E; a2[1] = -__expf(al0.y) * LOG2E;
        a2[2] = -__expf(al0.z) * LOG2E; a2[3] = -__expf(al0.w) * LOG2E;
        a2[4] = -__expf(al1.x) * LOG2E; a2[5] = -__expf(al1.y) * LOG2E;
        a2[6] = -__expf(al1.z) * LOG2E; a2[7] = -__expf(al1.w) * LOG2E;
    }
    const float Dd = Dp[d];
    const size_t idx = (((size_t)bb * CCH + c) * DIN + d) * NST + nh * 8;
    float h[8];
    *(float4*)&h[0] = *(const float4*)&hstart[idx];
    *(float4*)&h[4] = *(const float4*)&hstart[idx + 4];

    const float* pdt = dt + (size_t)row0 * DIN + d;
    const __hip_bfloat16* pu = u + (size_t)row0 * DIN + d;
    const __hip_bfloat16* pz = zs + (size_t)row0 * DIN + d;
    __hip_bfloat16* py = y + (size_t)row0 * DIN + d;

#pragma unroll 2
    for (int t = 0; t < TCH; t++) {
        const float dtv = pdt[t * DIN];
        const float uv  = __bfloat162float(pu[t * DIN]);
        const float du = dtv * uv;
        float bv[8], cv[8];
        *(float4*)&bv[0] = *(const float4*)&sB[t * NST + nh * 8];
        *(float4*)&bv[4] = *(const float4*)&sB[t * NST + nh * 8 + 4];
        *(float4*)&cv[0] = *(const float4*)&sC[t * NST + nh * 8];
        *(float4*)&cv[4] = *(const float4*)&sC[t * NST + nh * 8 + 4];
        float yp = 0.f;
#pragma unroll
        for (int j = 0; j < 8; j++) {
            const float e = EXP2F(dtv * a2[j]);
            h[j] = h[j] * e + du * bv[j];
            yp += h[j] * cv[j];
        }
        yp += __shfl_xor(yp, 1, 64);
        if (nh == 0) {
            const float zv = __bfloat162float(pz[t * DIN]);
            py[t * DIN] = __float2bfloat16((yp + uv * Dd) * zv);
        }
    }
}

extern "C" void kernel_launch(void* const* d_in, const int* in_sizes, int n_in,
                              void* d_out, int out_size, void* d_ws, size_t ws_size,
                              hipStream_t stream) {
    const float* x      = (const float*)d_in[0];
    const float* ln_g   = (const float*)d_in[1];
    const float* ln_b   = (const float*)d_in[2];
    const float* w_in   = (const float*)d_in[3];   // (4096,1024)
    const float* conv_w = (const float*)d_in[4];   // (2048,1,4)
    const float* conv_b = (const float*)d_in[5];
    const float* dtin_w = (const float*)d_in[6];   // (64,2048)
    const float* dtin_b = (const float*)d_in[7];
    const float* dt_w   = (const float*)d_in[8];   // (2048,64)
    const float* dt_b   = (const float*)d_in[9];
    const float* B_w    = (const float*)d_in[10];  // (16,2048)
    const float* C_w    = (const float*)d_in[11];
    const float* A_log  = (const float*)d_in[12];  // (2048,16)
    const float* Dp     = (const float*)d_in[13];
    const float* out_w  = (const float*)d_in[14];  // (1024,2048)
    float* out = (float*)d_out;

    char* ws = (char*)d_ws;
    auto alloc = [&](size_t bytes) { char* p = ws; ws += (bytes + 255) & ~255ull; return p; };
    __hip_bfloat16* w1b   = (__hip_bfloat16*)alloc((size_t)4096 * 1024 * 2);  // dead after gemm0
    __hip_bfloat16* wpb   = (__hip_bfloat16*)alloc((size_t)96 * 2048 * 2);
    __hip_bfloat16* dtwb  = (__hip_bfloat16*)alloc((size_t)2048 * 64 * 2);
    __hip_bfloat16* owb   = (__hip_bfloat16*)alloc((size_t)1024 * 2048 * 2);
    __hip_bfloat16* xnb   = (__hip_bfloat16*)alloc((size_t)MR * DMOD * 2);
    __hip_bfloat16* xprojb= (__hip_bfloat16*)alloc((size_t)MR * DIN * 2);
    __hip_bfloat16* zs    = (__hip_bfloat16*)alloc((size_t)MR * DIN * 2);
    __hip_bfloat16* xcb   = (__hip_bfloat16*)alloc((size_t)MR * DIN * 2);
    __hip_bfloat16* dtinb = (__hip_bfloat16*)alloc((size_t)MR * 64 * 2);
    float*          Bmf   = (float*)alloc((size_t)MR * NST * 4);
    float*          Cmf   = (float*)alloc((size_t)MR * NST * 4);
    float*          dtf   = (float*)alloc((size_t)MR * DIN * 4);
    __hip_bfloat16* yb    = (__hip_bfloat16*)alloc((size_t)MR * DIN * 2);
    float*          Aprod = (float*)alloc((size_t)BL * CCH * DIN * NST * 4);
    float*          Bacc  = (float*)alloc((size_t)BL * CCH * DIN * NST * 4);
    float*          hstart= (float*)alloc((size_t)BL * CCH * DIN * NST * 4);
    float*          part  = (float*)w1b;  // split-K partials (6.3MB) alias dead w1b (8MB)

    cvt_all<<<1024, 256, 0, stream>>>(w_in, dtin_w, B_w, C_w, dt_w, out_w, w1b, wpb, dtwb, owb);
    ln_kernel<<<MR, 256, 0, stream>>>(x, ln_g, ln_b, xnb);

    // [x_proj | silu(z)] = ln(x) @ in_proj_w^T : (2048 x 4096), K=1024 — 1024 blocks
    gemm_bt<0, 64, 128><<<dim3(32, 32, 1), 256, 0, stream>>>(xnb, 1024, w1b, 1024, MR, 4096, 1024,
                                                             xprojb, zs, nullptr);
    conv_silu_kernel<<<dim3(8, 32), 256, 0, stream>>>(xprojb, conv_w, conv_b, xcb);

    // [dtin|Bm|Cm] partials = x_conv @ [dtin_w;B_w;C_w]^T : (2048 x 96), K=2048, split-K=8 — 256 blocks
    gemm_bt<1, 64, 128><<<dim3(1, 32, KSPLIT), 256, 0, stream>>>(xcb, 2048, wpb, 2048, MR, 96, 2048 / KSPLIT,
                                                                 part, nullptr, nullptr);
    ep1_kernel<<<(MR * 96 + 255) / 256, 256, 0, stream>>>(part, dtin_b, dtinb, Bmf, Cmf);

    // dt = softplus(dtin @ dt_w^T + dt_b) : (2048 x 2048), K=64 — 512 blocks
    gemm_bt<2, 64, 128><<<dim3(16, 32, 1), 256, 0, stream>>>(dtinb, 64, dtwb, 64, MR, DIN, 64,
                                                             dtf, nullptr, dt_b);

    // chunked selective scan
    scan_p1<<<BL * CCH * 16, 256, 0, stream>>>(dtf, xcb, Bmf, A_log, Aprod, Bacc);
    scan_p2<<<BL * DIN * NST / 256, 256, 0, stream>>>(Aprod, Bacc, hstart);
    scan_p3<<<BL * CCH * 16, 256, 0, stream>>>(dtf, xcb, Bmf, Cmf, A_log, Dp, zs, hstart, yb);

    // out = y @ out_w^T + residual : (2048 x 1024), K=2048 — 512 blocks
    gemm_bt<3, 64, 64><<<dim3(16, 32, 1), 256, 0, stream>>>(yb, 2048, owb, 2048, MR, DMOD, 2048,
                                                            out, (void*)x, nullptr);
}